// Round 1
// baseline (3422.810 us; speedup 1.0000x reference)
//
#include <hip/hip_runtime.h>
#include <cstddef>

// ---------------------------------------------------------------------------
// GNN forward: embed+posenc -> 2x TransformerConv(8 heads x 32) -> 2x GCNConv
// N=50000, E=400000, IN=63, D=32, HC=256, fp32 everywhere.
// ---------------------------------------------------------------------------

#define NH 8
#define HCH 256   // heads * ch
#define D32 32
#define INCH 63

__device__ __forceinline__ int f2o(float f) {
    int i = __float_as_int(f);
    return i >= 0 ? i : (i ^ 0x7FFFFFFF);
}
__device__ __forceinline__ float o2f(int i) {
    return __int_as_float(i >= 0 ? i : (i ^ 0x7FFFFFFF));
}

// inv_freq[j] = 10000^(-2j/32) = 10^(-j/4)
__device__ const float c_invf[16] = {
    1.0f, 0.5623413251903491f, 0.31622776601683794f, 0.17782794100389228f,
    0.1f, 0.05623413251903491f, 0.031622776601683791f, 0.017782794100389228f,
    0.01f, 0.005623413251903491f, 0.0031622776601683794f, 0.0017782794100389228f,
    0.001f, 0.0005623413251903491f, 0.00031622776601683794f, 0.00017782794100389227f
};

// --- embed: H[N,32] = x[N,63] @ W[63,32] + b + posenc ---------------------
__global__ __launch_bounds__(256) void k_embed(
    const float* __restrict__ x, const float* __restrict__ W,
    const float* __restrict__ b, float* __restrict__ H, int N)
{
    __shared__ float xs[8][64];
    __shared__ float ws[INCH * D32];
    int row0 = blockIdx.x * 8;
    for (int i = threadIdx.x; i < INCH * D32; i += 256) ws[i] = W[i];
    for (int i = threadIdx.x; i < 8 * INCH; i += 256) {
        int r = i / INCH, cc = i % INCH;
        int gr = row0 + r;
        xs[r][cc] = (gr < N) ? x[(size_t)gr * INCH + cc] : 0.f;
    }
    __syncthreads();
    int lr = threadIdx.x >> 5, c = threadIdx.x & 31;
    int row = row0 + lr;
    if (row >= N) return;
    float acc = b[c];
#pragma unroll
    for (int k = 0; k < INCH; ++k) acc = fmaf(xs[lr][k], ws[k * D32 + c], acc);
    float phase = (float)row * c_invf[c >> 1];
    float pe = (c & 1) ? cosf(phase) : sinf(phase);
    H[(size_t)row * D32 + c] = acc + pe;
}

// --- init segment-max (ordered int) and denom ------------------------------
__global__ void k_init_md(int* __restrict__ M, float* __restrict__ DEN, int n) {
    int i = blockIdx.x * 256 + threadIdx.x;
    if (i < n) { M[i] = (int)0x80000000; DEN[i] = 0.f; }
}

// --- two 32->256 projections in one pass (q&k, or v&skip) ------------------
__global__ __launch_bounds__(256) void k_h32_to_2x256(
    const float* __restrict__ Hm,
    const float* __restrict__ W1, const float* __restrict__ b1,
    const float* __restrict__ W2, const float* __restrict__ b2,
    float* __restrict__ O1, float* __restrict__ O2, int N)
{
    __shared__ float hs[8][33];
    int row0 = blockIdx.x * 8;
    int c = threadIdx.x;
    {
        int r = threadIdx.x >> 5, k = threadIdx.x & 31;
        int gr = row0 + r;
        hs[r][k] = (gr < N) ? Hm[(size_t)gr * D32 + k] : 0.f;
    }
    __syncthreads();
    float a1[8], a2[8];
    float bb1 = b1[c], bb2 = b2[c];
#pragma unroll
    for (int r = 0; r < 8; ++r) { a1[r] = bb1; a2[r] = bb2; }
#pragma unroll 8
    for (int k = 0; k < 32; ++k) {
        float w1 = W1[k * HCH + c], w2 = W2[k * HCH + c];
#pragma unroll
        for (int r = 0; r < 8; ++r) {
            float h = hs[r][k];
            a1[r] = fmaf(h, w1, a1[r]);
            a2[r] = fmaf(h, w2, a2[r]);
        }
    }
#pragma unroll
    for (int r = 0; r < 8; ++r) {
        int gr = row0 + r;
        if (gr < N) {
            O1[(size_t)gr * HCH + c] = a1[r];
            O2[(size_t)gr * HCH + c] = a2[r];
        }
    }
}

// --- per-edge logits: wave per edge, q[dst].k[src] per head ----------------
__global__ __launch_bounds__(256) void k_logits(
    const float4* __restrict__ Q, const float4* __restrict__ K,
    const int* __restrict__ src, const int* __restrict__ dst,
    float* __restrict__ L, int* __restrict__ M, int E)
{
    int wid = (blockIdx.x * 256 + threadIdx.x) >> 6;
    int lane = threadIdx.x & 63;
    if (wid >= E) return;
    int s = src[wid], d = dst[wid];
    float4 qv = Q[(size_t)d * 64 + lane];
    float4 kv = K[(size_t)s * 64 + lane];
    float p = qv.x * kv.x + qv.y * kv.y + qv.z * kv.z + qv.w * kv.w;
    p += __shfl_xor(p, 1, 64);
    p += __shfl_xor(p, 2, 64);
    p += __shfl_xor(p, 4, 64);
    if ((lane & 7) == 0) {
        int h = lane >> 3;
        float lg = p * 0.17677669529663689f;  // 1/sqrt(32)
        L[(size_t)wid * NH + h] = lg;
        atomicMax(&M[(size_t)d * NH + h], f2o(lg));
    }
}

// --- e = exp(logit - m[dst]); denom += e -----------------------------------
__global__ void k_edenom(
    const int* __restrict__ dst, float* __restrict__ L,
    const int* __restrict__ M, float* __restrict__ DEN, int E8)
{
    int i = blockIdx.x * 256 + threadIdx.x;
    if (i >= E8) return;
    int e = i >> 3, h = i & 7;
    int d = dst[e];
    float m = o2f(M[(size_t)d * NH + h]);
    float ev = expf(L[i] - m);
    L[i] = ev;
    atomicAdd(&DEN[(size_t)d * NH + h], ev);
}

// --- scatter: O[dst] += (e/denom[dst]) * v[src] ----------------------------
__global__ __launch_bounds__(256) void k_scatter(
    const float4* __restrict__ V, const int* __restrict__ src,
    const int* __restrict__ dst, const float* __restrict__ L,
    const float* __restrict__ DEN, float* __restrict__ O, int E)
{
    int wid = (blockIdx.x * 256 + threadIdx.x) >> 6;
    int lane = threadIdx.x & 63;
    if (wid >= E) return;
    int s = src[wid], d = dst[wid];
    int h = lane >> 3;  // channels lane*4..lane*4+3 all in head lane>>3
    float alpha = L[(size_t)wid * NH + h] / DEN[(size_t)d * NH + h];
    float4 vv = V[(size_t)s * 64 + lane];
    float* op = O + (size_t)d * HCH + lane * 4;
    atomicAdd(op + 0, alpha * vv.x);
    atomicAdd(op + 1, alpha * vv.y);
    atomicAdd(op + 2, alpha * vv.z);
    atomicAdd(op + 3, alpha * vv.w);
}

// --- 256->32 projection: H = X @ W + b -------------------------------------
__global__ __launch_bounds__(256) void k_h256_to_32(
    const float* __restrict__ X, const float* __restrict__ W,
    const float* __restrict__ b, float* __restrict__ O, int N)
{
    __shared__ float xs[8][257];
    __shared__ float ws[HCH * D32];
    int row0 = blockIdx.x * 8;
    for (int i = threadIdx.x; i < HCH * D32; i += 256) ws[i] = W[i];
    for (int i = threadIdx.x; i < 8 * HCH; i += 256) {
        int r = i >> 8, k = i & 255;
        int gr = row0 + r;
        xs[r][k] = (gr < N) ? X[(size_t)gr * HCH + k] : 0.f;
    }
    __syncthreads();
    int c = threadIdx.x & 31, lr = threadIdx.x >> 5;
    int row = row0 + lr;
    if (row >= N) return;
    float acc = b[c];
#pragma unroll 8
    for (int k = 0; k < HCH; ++k) acc = fmaf(xs[lr][k], ws[k * D32 + c], acc);
    O[(size_t)row * D32 + c] = acc;
}

// --- 32->32 matmul (no bias): O = X @ W ------------------------------------
__global__ __launch_bounds__(256) void k_h32_to_32(
    const float* __restrict__ X, const float* __restrict__ W,
    float* __restrict__ O, int N)
{
    __shared__ float xs[8][33];
    __shared__ float ws[D32 * D32];
    int row0 = blockIdx.x * 8;
    int c = threadIdx.x & 31, lr = threadIdx.x >> 5;
    for (int i = threadIdx.x; i < D32 * D32; i += 256) ws[i] = W[i];
    {
        int gr = row0 + lr;
        xs[lr][c] = (gr < N) ? X[(size_t)gr * D32 + c] : 0.f;
    }
    __syncthreads();
    int row = row0 + lr;
    if (row >= N) return;
    float acc = 0.f;
#pragma unroll
    for (int k = 0; k < D32; ++k) acc = fmaf(xs[lr][k], ws[k * D32 + c], acc);
    O[(size_t)row * D32 + c] = acc;
}

// --- GCN degree / norm -----------------------------------------------------
__global__ void k_deg_init(float* __restrict__ DEG, int N) {
    int i = blockIdx.x * 256 + threadIdx.x;
    if (i < N) DEG[i] = 1.f;  // self loop
}
__global__ void k_deg_acc(const int* __restrict__ dst, float* __restrict__ DEG, int E) {
    int i = blockIdx.x * 256 + threadIdx.x;
    if (i < E) atomicAdd(&DEG[dst[i]], 1.f);
}
__global__ void k_dis(const float* __restrict__ DEG, float* __restrict__ DIS, int N) {
    int i = blockIdx.x * 256 + threadIdx.x;
    if (i < N) DIS[i] = rsqrtf(DEG[i]);
}

// --- GCN: out init with self-loop + bias; then edge scatter ----------------
__global__ void k_gcn_init(
    const float* __restrict__ XW, const float* __restrict__ DIS,
    const float* __restrict__ b, float* __restrict__ O, int N32)
{
    int i = blockIdx.x * 256 + threadIdx.x;
    if (i >= N32) return;
    int n = i >> 5, c = i & 31;
    float dn = DIS[n];
    O[i] = dn * dn * XW[i] + b[c];
}
__global__ void k_gcn_scatter(
    const float* __restrict__ XW, const float* __restrict__ DIS,
    const int* __restrict__ src, const int* __restrict__ dst,
    float* __restrict__ O, int E32)
{
    int i = blockIdx.x * 256 + threadIdx.x;
    if (i >= E32) return;
    int e = i >> 5, c = i & 31;
    int s = src[e], d = dst[e];
    atomicAdd(&O[(size_t)d * D32 + c], DIS[s] * DIS[d] * XW[(size_t)s * D32 + c]);
}

// ---------------------------------------------------------------------------
extern "C" void kernel_launch(void* const* d_in, const int* in_sizes, int n_in,
                              void* d_out, int out_size, void* d_ws, size_t ws_size,
                              hipStream_t stream)
{
    const float* x  = (const float*)d_in[0];
    const int*   ei = (const int*)d_in[1];
    const int N = in_sizes[0] / INCH;
    const int E = in_sizes[1] / 2;
    const int* src = ei;
    const int* dst = ei + E;

    const float* W_embed = (const float*)d_in[2];
    const float* b_embed = (const float*)d_in[3];
    // per-layer transformer weights: Wq,bq,Wk,bk,Wv,bv,Ws,bs,Wh,bh at 4..13 and 14..23
    const float* Wg3 = (const float*)d_in[24];
    const float* bg3 = (const float*)d_in[25];
    const float* Wg4 = (const float*)d_in[26];
    const float* bg4 = (const float*)d_in[27];

    float* A   = (float*)d_ws;                    // N*256 (q, then v, then gcn xw)
    float* B   = A + (size_t)N * HCH;             // N*256 (k, then attn out, then gcn out)
    float* L   = B + (size_t)N * HCH;             // E*8   (logits -> e)
    int*   M   = (int*)(L + (size_t)E * NH);      // N*8   (seg max; later DIS as float)
    float* DEN = (float*)(M + (size_t)N * NH);    // N*8   (denom; later deg)
    float* H   = DEN + (size_t)N * NH;            // N*32  (current node features)
    float* out = (float*)d_out;

    const int nb8 = (N + 7) / 8;

    k_embed<<<nb8, 256, 0, stream>>>(x, W_embed, b_embed, H, N);

    for (int layer = 0; layer < 2; ++layer) {
        int base = 4 + layer * 10;
        const float* Wq = (const float*)d_in[base + 0];
        const float* bq = (const float*)d_in[base + 1];
        const float* Wk = (const float*)d_in[base + 2];
        const float* bk = (const float*)d_in[base + 3];
        const float* Wv = (const float*)d_in[base + 4];
        const float* bv = (const float*)d_in[base + 5];
        const float* Wsk = (const float*)d_in[base + 6];
        const float* bsk = (const float*)d_in[base + 7];
        const float* Wh = (const float*)d_in[base + 8];
        const float* bh = (const float*)d_in[base + 9];

        k_init_md<<<(N * NH + 255) / 256, 256, 0, stream>>>(M, DEN, N * NH);
        k_h32_to_2x256<<<nb8, 256, 0, stream>>>(H, Wq, bq, Wk, bk, A, B, N);
        k_logits<<<(E + 3) / 4, 256, 0, stream>>>(
            (const float4*)A, (const float4*)B, src, dst, L, M, E);
        k_edenom<<<(E * NH + 255) / 256, 256, 0, stream>>>(dst, L, M, DEN, E * NH);
        // v into A (q dead), skip-connection h@Ws+bs into B (k dead) = out init
        k_h32_to_2x256<<<nb8, 256, 0, stream>>>(H, Wv, bv, Wsk, bsk, A, B, N);
        k_scatter<<<(E + 3) / 4, 256, 0, stream>>>(
            (const float4*)A, src, dst, L, DEN, B, E);
        k_h256_to_32<<<nb8, 256, 0, stream>>>(B, Wh, bh, H, N);
    }

    // GCN shared norm (graph is fixed: same for both layers)
    float* DEG = DEN;           // reuse, N floats
    float* DIS = (float*)M;     // reuse, N floats
    k_deg_init<<<(N + 255) / 256, 256, 0, stream>>>(DEG, N);
    k_deg_acc<<<(E + 255) / 256, 256, 0, stream>>>(dst, DEG, E);
    k_dis<<<(N + 255) / 256, 256, 0, stream>>>(DEG, DIS, N);

    // GCN layer 1: xw = H@Wg3 -> A ; out -> B
    k_h32_to_32<<<nb8, 256, 0, stream>>>(H, Wg3, A, N);
    k_gcn_init<<<(N * D32 + 255) / 256, 256, 0, stream>>>(A, DIS, bg3, B, N * D32);
    k_gcn_scatter<<<(E * D32 + 255) / 256, 256, 0, stream>>>(A, DIS, src, dst, B, E * D32);

    // GCN layer 2: xw = B@Wg4 -> A ; out -> d_out
    k_h32_to_32<<<nb8, 256, 0, stream>>>(B, Wg4, A, N);
    k_gcn_init<<<(N * D32 + 255) / 256, 256, 0, stream>>>(A, DIS, bg4, out, N * D32);
    k_gcn_scatter<<<(E * D32 + 255) / 256, 256, 0, stream>>>(A, DIS, src, dst, out, E * D32);
}

// Round 2
// 718.247 us; speedup vs baseline: 4.7655x; 4.7655x over previous
//
#include <hip/hip_runtime.h>
#include <cstddef>

// ---------------------------------------------------------------------------
// GNN forward: embed+posenc -> 2x TransformerConv(8 heads x 32) -> 2x GCNConv
// N=50000, E=400000, IN=63, D=32, HC=256, fp32.
// Strategy: build dst-CSR once (no per-edge atomics afterwards); attention is
// a fused wave-per-dst-node kernel with online softmax; skip path composed
// into a 32x32 matrix (Ws@Wh); GCN layers are CSR gathers.
// ---------------------------------------------------------------------------

#define NH 8
#define HCH 256
#define D32 32
#define INCH 63

// inv_freq[j] = 10000^(-2j/32) = 10^(-j/4)
__device__ const float c_invf[16] = {
    1.0f, 0.5623413251903491f, 0.31622776601683794f, 0.17782794100389228f,
    0.1f, 0.05623413251903491f, 0.031622776601683791f, 0.017782794100389228f,
    0.01f, 0.005623413251903491f, 0.0031622776601683794f, 0.0017782794100389228f,
    0.001f, 0.0005623413251903491f, 0.00031622776601683794f, 0.00017782794100389227f
};

// --- embed: H[N,32] = x[N,63] @ W[63,32] + b + posenc ----------------------
__global__ __launch_bounds__(256) void k_embed(
    const float* __restrict__ x, const float* __restrict__ W,
    const float* __restrict__ b, float* __restrict__ H, int N)
{
    __shared__ float xs[8][64];
    __shared__ float ws[INCH * D32];
    int row0 = blockIdx.x * 8;
    for (int i = threadIdx.x; i < INCH * D32; i += 256) ws[i] = W[i];
    for (int i = threadIdx.x; i < 8 * INCH; i += 256) {
        int r = i / INCH, cc = i % INCH;
        int gr = row0 + r;
        xs[r][cc] = (gr < N) ? x[(size_t)gr * INCH + cc] : 0.f;
    }
    __syncthreads();
    int lr = threadIdx.x >> 5, c = threadIdx.x & 31;
    int row = row0 + lr;
    if (row >= N) return;
    float acc = b[c];
#pragma unroll
    for (int k = 0; k < INCH; ++k) acc = fmaf(xs[lr][k], ws[k * D32 + c], acc);
    float phase = (float)row * c_invf[c >> 1];
    float pe = (c & 1) ? cosf(phase) : sinf(phase);
    H[(size_t)row * D32 + c] = acc + pe;
}

// --- CSR build -------------------------------------------------------------
__global__ void k_zero_i(int* __restrict__ p, int n) {
    int i = blockIdx.x * 256 + threadIdx.x;
    if (i < n) p[i] = 0;
}
__global__ void k_count(const int* __restrict__ dst, int* __restrict__ cnt, int E) {
    int i = blockIdx.x * 256 + threadIdx.x;
    if (i < E) atomicAdd(&cnt[dst[i]], 1);
}
// inclusive scan of 256-chunks; partials for second level (N<=65536)
__global__ void k_scan1(const int* __restrict__ cnt, int* __restrict__ rowptr,
                        int* __restrict__ partials, int N)
{
    __shared__ int s[256];
    int g = blockIdx.x * 256 + threadIdx.x;
    s[threadIdx.x] = (g < N) ? cnt[g] : 0;
    __syncthreads();
    for (int off = 1; off < 256; off <<= 1) {
        int t = (threadIdx.x >= off) ? s[threadIdx.x - off] : 0;
        __syncthreads();
        s[threadIdx.x] += t;
        __syncthreads();
    }
    if (g < N) rowptr[g + 1] = s[threadIdx.x];
    if (threadIdx.x == 255) partials[blockIdx.x] = s[255];
}
__global__ void k_scan2(int* __restrict__ partials, int nb) {
    __shared__ int s[256];
    int t = threadIdx.x;
    s[t] = (t < nb) ? partials[t] : 0;
    __syncthreads();
    for (int off = 1; off < 256; off <<= 1) {
        int v = (t >= off) ? s[t - off] : 0;
        __syncthreads();
        s[t] += v;
        __syncthreads();
    }
    partials[t] = (t == 0) ? 0 : s[t - 1];  // exclusive
}
__global__ void k_scan3(int* __restrict__ rowptr, const int* __restrict__ partials, int N) {
    int g = blockIdx.x * 256 + threadIdx.x;
    if (g < N) rowptr[g + 1] += partials[blockIdx.x];
    if (g == 0) rowptr[0] = 0;
}
__global__ void k_setcur(const int* __restrict__ rowptr, int* __restrict__ cur, int N) {
    int i = blockIdx.x * 256 + threadIdx.x;
    if (i < N) cur[i] = rowptr[i];
}
__global__ void k_fill(const int* __restrict__ src, const int* __restrict__ dst,
                       int* __restrict__ cur, int* __restrict__ colsrc, int E)
{
    int e = blockIdx.x * 256 + threadIdx.x;
    if (e < E) {
        int p = atomicAdd(&cur[dst[e]], 1);
        colsrc[p] = src[e];
    }
}
__global__ void k_disk(const int* __restrict__ rowptr, float* __restrict__ DIS, int N) {
    int i = blockIdx.x * 256 + threadIdx.x;
    if (i < N) DIS[i] = rsqrtf((float)(rowptr[i + 1] - rowptr[i]) + 1.0f);
}

// --- compose skip path: Wc = Ws@Wh (32x32), bc = bs@Wh + bh ----------------
__global__ void k_compose(const float* __restrict__ Wsk, const float* __restrict__ bsk,
                          const float* __restrict__ Wh, const float* __restrict__ bh,
                          float* __restrict__ Wc, float* __restrict__ bc)
{
    for (int i = threadIdx.x; i < D32 * D32 + D32; i += 256) {
        if (i < D32 * D32) {
            int r = i >> 5, c = i & 31;
            float a = 0.f;
            for (int k = 0; k < HCH; ++k) a = fmaf(Wsk[r * HCH + k], Wh[k * D32 + c], a);
            Wc[i] = a;
        } else {
            int c = i - D32 * D32;
            float a = bh[c];
            for (int k = 0; k < HCH; ++k) a = fmaf(bsk[k], Wh[k * D32 + c], a);
            bc[c] = a;
        }
    }
}

// --- two 32->256 projections in one pass (k & v) ---------------------------
__global__ __launch_bounds__(256) void k_h32_to_2x256(
    const float* __restrict__ Hm,
    const float* __restrict__ W1, const float* __restrict__ b1,
    const float* __restrict__ W2, const float* __restrict__ b2,
    float* __restrict__ O1, float* __restrict__ O2, int N)
{
    __shared__ float hs[8][33];
    int row0 = blockIdx.x * 8;
    int c = threadIdx.x;
    {
        int r = threadIdx.x >> 5, k = threadIdx.x & 31;
        int gr = row0 + r;
        hs[r][k] = (gr < N) ? Hm[(size_t)gr * D32 + k] : 0.f;
    }
    __syncthreads();
    float a1[8], a2[8];
    float bb1 = b1[c], bb2 = b2[c];
#pragma unroll
    for (int r = 0; r < 8; ++r) { a1[r] = bb1; a2[r] = bb2; }
#pragma unroll 8
    for (int k = 0; k < 32; ++k) {
        float w1 = W1[k * HCH + c], w2 = W2[k * HCH + c];
#pragma unroll
        for (int r = 0; r < 8; ++r) {
            float h = hs[r][k];
            a1[r] = fmaf(h, w1, a1[r]);
            a2[r] = fmaf(h, w2, a2[r]);
        }
    }
#pragma unroll
    for (int r = 0; r < 8; ++r) {
        int gr = row0 + r;
        if (gr < N) {
            O1[(size_t)gr * HCH + c] = a1[r];
            O2[(size_t)gr * HCH + c] = a2[r];
        }
    }
}

// --- fused attention: wave per dst node ------------------------------------
// q = H[d]@Wq+bq (on the fly); online softmax over CSR in-edges (K,V rows);
// out = (attn_row)@Wh + H[d]@Wc + bc, written in-place to H[d].
__global__ __launch_bounds__(256) void k_attn(
    const float4* __restrict__ K4, const float4* __restrict__ V4,
    float* H,  // no restrict: in/out
    const int* __restrict__ rowptr, const int* __restrict__ colsrc,
    const float4* __restrict__ Wq4, const float4* __restrict__ bq4,
    const float* __restrict__ Wh, const float* __restrict__ Wc,
    const float* __restrict__ bc, int N)
{
    __shared__ float hh[4][32];
    __shared__ float os[4][256];
    int w = threadIdx.x >> 6, lane = threadIdx.x & 63;
    int d = blockIdx.x * 4 + w;
    bool act = d < N;

    if (act && lane < 32) hh[w][lane] = H[(size_t)d * D32 + lane];
    __syncthreads();

    // q for this node's 4 channels (lane*4 .. lane*4+3)
    float4 qv = make_float4(0.f, 0.f, 0.f, 0.f);
    if (act) {
        qv = bq4[lane];
#pragma unroll 8
        for (int k = 0; k < 32; ++k) {
            float h = hh[w][k];
            float4 wv = Wq4[k * 64 + lane];
            qv.x = fmaf(h, wv.x, qv.x);
            qv.y = fmaf(h, wv.y, qv.y);
            qv.z = fmaf(h, wv.z, qv.z);
            qv.w = fmaf(h, wv.w, qv.w);
        }
    }

    float m = -INFINITY, l = 0.f;
    float4 acc = make_float4(0.f, 0.f, 0.f, 0.f);
    if (act) {
        int p1 = rowptr[d + 1];
        for (int p = rowptr[d]; p < p1; ++p) {
            int s = colsrc[p];
            float4 kv = K4[(size_t)s * 64 + lane];
            float t = qv.x * kv.x + qv.y * kv.y + qv.z * kv.z + qv.w * kv.w;
            t += __shfl_xor(t, 1, 64);
            t += __shfl_xor(t, 2, 64);
            t += __shfl_xor(t, 4, 64);      // per-head (8-lane group) logit
            float lg = t * 0.17677669529663689f;  // 1/sqrt(32)
            float mn = fmaxf(m, lg);
            float c1 = expf(m - mn);        // m=-inf first iter -> 0
            float wg = expf(lg - mn);
            float4 vv = V4[(size_t)s * 64 + lane];
            l = l * c1 + wg;
            acc.x = fmaf(acc.x, c1, wg * vv.x);
            acc.y = fmaf(acc.y, c1, wg * vv.y);
            acc.z = fmaf(acc.z, c1, wg * vv.z);
            acc.w = fmaf(acc.w, c1, wg * vv.w);
            m = mn;
        }
    }
    float inv = (l > 0.f) ? 1.f / l : 0.f;
    os[w][lane * 4 + 0] = acc.x * inv;
    os[w][lane * 4 + 1] = acc.y * inv;
    os[w][lane * 4 + 2] = acc.z * inv;
    os[w][lane * 4 + 3] = acc.w * inv;
    __syncthreads();

    if (act && lane < 32) {
        int c = lane;
        float a2 = bc[c];
#pragma unroll 8
        for (int k = 0; k < 32; ++k) a2 = fmaf(hh[w][k], Wc[k * D32 + c], a2);
#pragma unroll 8
        for (int k = 0; k < 256; ++k) a2 = fmaf(os[w][k], Wh[k * D32 + c], a2);
        H[(size_t)d * D32 + c] = a2;
    }
}

// --- 32->32 matmul (no bias): O = X @ W ------------------------------------
__global__ __launch_bounds__(256) void k_h32_to_32(
    const float* __restrict__ X, const float* __restrict__ W,
    float* __restrict__ O, int N)
{
    __shared__ float xs[8][33];
    __shared__ float ws[D32 * D32];
    int row0 = blockIdx.x * 8;
    int c = threadIdx.x & 31, lr = threadIdx.x >> 5;
    for (int i = threadIdx.x; i < D32 * D32; i += 256) ws[i] = W[i];
    {
        int gr = row0 + lr;
        xs[lr][c] = (gr < N) ? X[(size_t)gr * D32 + c] : 0.f;
    }
    __syncthreads();
    int row = row0 + lr;
    if (row >= N) return;
    float acc = 0.f;
#pragma unroll
    for (int k = 0; k < D32; ++k) acc = fmaf(xs[lr][k], ws[k * D32 + c], acc);
    O[(size_t)row * D32 + c] = acc;
}

// --- GCN gather (CSR, no atomics): out = DIS[d]*(sum + DIS[d]*XW[d]) + b ---
__global__ __launch_bounds__(256) void k_gcn(
    const float* __restrict__ XW, const float* __restrict__ DIS,
    const int* __restrict__ rowptr, const int* __restrict__ colsrc,
    const float* __restrict__ b, float* __restrict__ Out, int N)
{
    int g = threadIdx.x >> 5;     // 8 nodes per block
    int c = threadIdx.x & 31;
    int d = blockIdx.x * 8 + g;
    if (d >= N) return;
    float dd = DIS[d];
    float acc = dd * XW[(size_t)d * D32 + c];   // self-loop term / dd
    int p1 = rowptr[d + 1];
    for (int p = rowptr[d]; p < p1; ++p) {
        int s = colsrc[p];
        acc += DIS[s] * XW[(size_t)s * D32 + c];
    }
    Out[(size_t)d * D32 + c] = dd * acc + b[c];
}

// ---------------------------------------------------------------------------
extern "C" void kernel_launch(void* const* d_in, const int* in_sizes, int n_in,
                              void* d_out, int out_size, void* d_ws, size_t ws_size,
                              hipStream_t stream)
{
    const float* x  = (const float*)d_in[0];
    const int*   ei = (const int*)d_in[1];
    const int N = in_sizes[0] / INCH;
    const int E = in_sizes[1] / 2;
    const int* src = ei;
    const int* dst = ei + E;

    const float* W_embed = (const float*)d_in[2];
    const float* b_embed = (const float*)d_in[3];
    const float* Wg3 = (const float*)d_in[24];
    const float* bg3 = (const float*)d_in[25];
    const float* Wg4 = (const float*)d_in[26];
    const float* bg4 = (const float*)d_in[27];

    // workspace layout (~111 MB)
    float* K      = (float*)d_ws;                   // N*256
    float* V      = K + (size_t)N * HCH;            // N*256
    float* H      = V + (size_t)N * HCH;            // N*32
    int*   rowptr = (int*)(H + (size_t)N * D32);    // N+1
    int*   colsrc = rowptr + (N + 1);               // E
    int*   cursor = colsrc + E;                     // N
    int*   partials = cursor + N;                   // 256
    float* DIS    = (float*)(partials + 256);       // N
    float* Wc     = DIS + N;                        // 32*32
    float* bc     = Wc + D32 * D32;                 // 32
    float* out    = (float*)d_out;

    const int nb8 = (N + 7) / 8;
    const int nbN = (N + 255) / 256;
    const int nbE = (E + 255) / 256;

    k_embed<<<nb8, 256, 0, stream>>>(x, W_embed, b_embed, H, N);

    // CSR build (dst-grouped)
    k_zero_i<<<nbN, 256, 0, stream>>>(cursor, N);
    k_count<<<nbE, 256, 0, stream>>>(dst, cursor, E);
    k_scan1<<<nbN, 256, 0, stream>>>(cursor, rowptr, partials, N);
    k_scan2<<<1, 256, 0, stream>>>(partials, nbN);   // requires nbN <= 256
    k_scan3<<<nbN, 256, 0, stream>>>(rowptr, partials, N);
    k_setcur<<<nbN, 256, 0, stream>>>(rowptr, cursor, N);
    k_fill<<<nbE, 256, 0, stream>>>(src, dst, cursor, colsrc, E);
    k_disk<<<nbN, 256, 0, stream>>>(rowptr, DIS, N);

    for (int layer = 0; layer < 2; ++layer) {
        int base = 4 + layer * 10;
        const float* Wq = (const float*)d_in[base + 0];
        const float* bq = (const float*)d_in[base + 1];
        const float* Wk = (const float*)d_in[base + 2];
        const float* bk = (const float*)d_in[base + 3];
        const float* Wv = (const float*)d_in[base + 4];
        const float* bv = (const float*)d_in[base + 5];
        const float* Wsk = (const float*)d_in[base + 6];
        const float* bsk = (const float*)d_in[base + 7];
        const float* Wh = (const float*)d_in[base + 8];
        const float* bh = (const float*)d_in[base + 9];

        k_compose<<<1, 256, 0, stream>>>(Wsk, bsk, Wh, bh, Wc, bc);
        k_h32_to_2x256<<<nb8, 256, 0, stream>>>(H, Wk, bk, Wv, bv, K, V, N);
        k_attn<<<(N + 3) / 4, 256, 0, stream>>>(
            (const float4*)K, (const float4*)V, H, rowptr, colsrc,
            (const float4*)Wq, (const float4*)bq, Wh, Wc, bc, N);
    }

    // GCN layer 1: XW = H@Wg3 -> K ; out -> V
    k_h32_to_32<<<nb8, 256, 0, stream>>>(H, Wg3, K, N);
    k_gcn<<<nb8, 256, 0, stream>>>(K, DIS, rowptr, colsrc, bg3, V, N);
    // GCN layer 2: XW = V@Wg4 -> K ; out -> d_out
    k_h32_to_32<<<nb8, 256, 0, stream>>>(V, Wg4, K, N);
    k_gcn<<<nb8, 256, 0, stream>>>(K, DIS, rowptr, colsrc, bg4, out, N);
}

// Round 3
// 703.672 us; speedup vs baseline: 4.8642x; 1.0207x over previous
//
#include <hip/hip_runtime.h>
#include <cstddef>

// ---------------------------------------------------------------------------
// GNN forward: embed+posenc -> 2x TransformerConv(8 heads x 32) -> 2x GCNConv
// N=50000, E=400000, IN=63, D=32, HC=256.
// R3: K/V stored bf16 interleaved (1KB/node row); wave-per-node fused attn
// with online softmax; dst-CSR built once; GCN = CSR gathers (fp32).
// ---------------------------------------------------------------------------

#define NH 8
#define HCH 256
#define D32 32
#define INCH 63

__device__ __forceinline__ unsigned short f2bf(float f) {
    unsigned u = __float_as_uint(f);
    u += 0x7fff + ((u >> 16) & 1);   // RNE
    return (unsigned short)(u >> 16);
}

// inv_freq[j] = 10000^(-2j/32) = 10^(-j/4)
__device__ const float c_invf[16] = {
    1.0f, 0.5623413251903491f, 0.31622776601683794f, 0.17782794100389228f,
    0.1f, 0.05623413251903491f, 0.031622776601683791f, 0.017782794100389228f,
    0.01f, 0.005623413251903491f, 0.0031622776601683794f, 0.0017782794100389228f,
    0.001f, 0.0005623413251903491f, 0.00031622776601683794f, 0.00017782794100389227f
};

// --- embed: H[N,32] = x[N,63] @ W[63,32] + b + posenc ----------------------
__global__ __launch_bounds__(256) void k_embed(
    const float* __restrict__ x, const float* __restrict__ W,
    const float* __restrict__ b, float* __restrict__ H, int N)
{
    __shared__ float xs[8][64];
    __shared__ float ws[INCH * D32];
    int row0 = blockIdx.x * 8;
    for (int i = threadIdx.x; i < INCH * D32; i += 256) ws[i] = W[i];
    for (int i = threadIdx.x; i < 8 * INCH; i += 256) {
        int r = i / INCH, cc = i % INCH;
        int gr = row0 + r;
        xs[r][cc] = (gr < N) ? x[(size_t)gr * INCH + cc] : 0.f;
    }
    __syncthreads();
    int lr = threadIdx.x >> 5, c = threadIdx.x & 31;
    int row = row0 + lr;
    if (row >= N) return;
    float acc = b[c];
#pragma unroll
    for (int k = 0; k < INCH; ++k) acc = fmaf(xs[lr][k], ws[k * D32 + c], acc);
    float phase = (float)row * c_invf[c >> 1];
    float pe = (c & 1) ? cosf(phase) : sinf(phase);
    H[(size_t)row * D32 + c] = acc + pe;
}

// --- CSR build -------------------------------------------------------------
__global__ void k_zero_i(int* __restrict__ p, int n) {
    int i = blockIdx.x * 256 + threadIdx.x;
    if (i < n) p[i] = 0;
}
__global__ void k_count(const int* __restrict__ dst, int* __restrict__ cnt, int E) {
    int i = blockIdx.x * 256 + threadIdx.x;
    if (i < E) atomicAdd(&cnt[dst[i]], 1);
}
__global__ void k_scan1(const int* __restrict__ cnt, int* __restrict__ rowptr,
                        int* __restrict__ partials, int N)
{
    __shared__ int s[256];
    int g = blockIdx.x * 256 + threadIdx.x;
    s[threadIdx.x] = (g < N) ? cnt[g] : 0;
    __syncthreads();
    for (int off = 1; off < 256; off <<= 1) {
        int t = (threadIdx.x >= off) ? s[threadIdx.x - off] : 0;
        __syncthreads();
        s[threadIdx.x] += t;
        __syncthreads();
    }
    if (g < N) rowptr[g + 1] = s[threadIdx.x];
    if (threadIdx.x == 255) partials[blockIdx.x] = s[255];
}
__global__ void k_scan2(int* __restrict__ partials, int nb) {
    __shared__ int s[256];
    int t = threadIdx.x;
    s[t] = (t < nb) ? partials[t] : 0;
    __syncthreads();
    for (int off = 1; off < 256; off <<= 1) {
        int v = (t >= off) ? s[t - off] : 0;
        __syncthreads();
        s[t] += v;
        __syncthreads();
    }
    partials[t] = (t == 0) ? 0 : s[t - 1];  // exclusive
}
__global__ void k_scan3(int* __restrict__ rowptr, const int* __restrict__ partials, int N) {
    int g = blockIdx.x * 256 + threadIdx.x;
    if (g < N) rowptr[g + 1] += partials[blockIdx.x];
    if (g == 0) rowptr[0] = 0;
}
__global__ void k_setcur(const int* __restrict__ rowptr, int* __restrict__ cur, int N) {
    int i = blockIdx.x * 256 + threadIdx.x;
    if (i < N) cur[i] = rowptr[i];
}
__global__ void k_fill(const int* __restrict__ src, const int* __restrict__ dst,
                       int* __restrict__ cur, int* __restrict__ colsrc, int E)
{
    int e = blockIdx.x * 256 + threadIdx.x;
    if (e < E) {
        int p = atomicAdd(&cur[dst[e]], 1);
        colsrc[p] = src[e];
    }
}
__global__ void k_disk(const int* __restrict__ rowptr, float* __restrict__ DIS, int N) {
    int i = blockIdx.x * 256 + threadIdx.x;
    if (i < N) DIS[i] = rsqrtf((float)(rowptr[i + 1] - rowptr[i]) + 1.0f);
}

// --- compose skip for BOTH layers: Wc = Ws@Wh (32x32), bc = bs@Wh + bh -----
// WCB layout per layer: [1024 floats Wc][32 floats bc] stride 1056
__global__ void k_compose2(
    const float* __restrict__ Wsk1, const float* __restrict__ bsk1,
    const float* __restrict__ Wh1,  const float* __restrict__ bh1,
    const float* __restrict__ Wsk2, const float* __restrict__ bsk2,
    const float* __restrict__ Wh2,  const float* __restrict__ bh2,
    float* __restrict__ WCB)
{
    const float* Wsk = blockIdx.x ? Wsk2 : Wsk1;
    const float* bsk = blockIdx.x ? bsk2 : bsk1;
    const float* Wh  = blockIdx.x ? Wh2  : Wh1;
    const float* bh  = blockIdx.x ? bh2  : bh1;
    float* o = WCB + blockIdx.x * 1056;
    for (int i = threadIdx.x; i < D32 * D32 + D32; i += 256) {
        if (i < D32 * D32) {
            int r = i >> 5, c = i & 31;
            float a = 0.f;
            for (int k = 0; k < HCH; ++k) a = fmaf(Wsk[r * HCH + k], Wh[k * D32 + c], a);
            o[i] = a;
        } else {
            int c = i - D32 * D32;
            float a = bh[c];
            for (int k = 0; k < HCH; ++k) a = fmaf(bsk[k], Wh[k * D32 + c], a);
            o[1024 + c] = a;
        }
    }
}

// --- K & V projections -> interleaved bf16 rows ----------------------------
// KV[n] = [256 bf16 of k | 256 bf16 of v]  (1KB per node)
__global__ __launch_bounds__(256) void k_h32_to_kv(
    const float* __restrict__ Hm,
    const float* __restrict__ W1, const float* __restrict__ b1,
    const float* __restrict__ W2, const float* __restrict__ b2,
    unsigned short* __restrict__ KV, int N)
{
    __shared__ float hs[8][33];
    int row0 = blockIdx.x * 8;
    int c = threadIdx.x;
    {
        int r = threadIdx.x >> 5, k = threadIdx.x & 31;
        int gr = row0 + r;
        hs[r][k] = (gr < N) ? Hm[(size_t)gr * D32 + k] : 0.f;
    }
    __syncthreads();
    float a1[8], a2[8];
    float bb1 = b1[c], bb2 = b2[c];
#pragma unroll
    for (int r = 0; r < 8; ++r) { a1[r] = bb1; a2[r] = bb2; }
#pragma unroll 8
    for (int k = 0; k < 32; ++k) {
        float w1 = W1[k * HCH + c], w2 = W2[k * HCH + c];
#pragma unroll
        for (int r = 0; r < 8; ++r) {
            float h = hs[r][k];
            a1[r] = fmaf(h, w1, a1[r]);
            a2[r] = fmaf(h, w2, a2[r]);
        }
    }
#pragma unroll
    for (int r = 0; r < 8; ++r) {
        int gr = row0 + r;
        if (gr < N) {
            KV[(size_t)gr * 512 + c]       = f2bf(a1[r]);
            KV[(size_t)gr * 512 + 256 + c] = f2bf(a2[r]);
        }
    }
}

// --- fused attention: wave per dst node, bf16 KV ---------------------------
// lanes 0-31: K channels lane*8..+7 (4 lanes/head); lanes 32-63: same V chans.
__global__ __launch_bounds__(256) void k_attn(
    const uint4* __restrict__ KV4, float* H,
    const int* __restrict__ rowptr, const int* __restrict__ colsrc,
    const float4* __restrict__ Wq4, const float4* __restrict__ bq4,
    const float* __restrict__ Wh, const float* __restrict__ WCBl, int N)
{
    __shared__ float hh[4][32];
    __shared__ float os[4][264];
    int w = threadIdx.x >> 6, lane = threadIdx.x & 63;
    int d = blockIdx.x * 4 + w;
    bool act = d < N;
    if (act && lane < 32) hh[w][lane] = H[(size_t)d * D32 + lane];
    __syncthreads();

    int j = lane & 31;   // channel-block: channels j*8..j*8+7, head j>>2
    float q[8];
    {
        float4 b0 = bq4[j * 2], b1 = bq4[j * 2 + 1];
        q[0] = b0.x; q[1] = b0.y; q[2] = b0.z; q[3] = b0.w;
        q[4] = b1.x; q[5] = b1.y; q[6] = b1.z; q[7] = b1.w;
        if (act) {
#pragma unroll 4
            for (int k = 0; k < 32; ++k) {
                float h = hh[w][k];
                float4 w0 = Wq4[k * 64 + j * 2], w1 = Wq4[k * 64 + j * 2 + 1];
                q[0] = fmaf(h, w0.x, q[0]); q[1] = fmaf(h, w0.y, q[1]);
                q[2] = fmaf(h, w0.z, q[2]); q[3] = fmaf(h, w0.w, q[3]);
                q[4] = fmaf(h, w1.x, q[4]); q[5] = fmaf(h, w1.y, q[5]);
                q[6] = fmaf(h, w1.z, q[6]); q[7] = fmaf(h, w1.w, q[7]);
            }
        }
    }
    float m = -INFINITY, l = 0.f;
    float acc[8] = {0.f, 0.f, 0.f, 0.f, 0.f, 0.f, 0.f, 0.f};
    if (act) {
        int p1 = rowptr[d + 1];
        for (int p = rowptr[d]; p < p1; ++p) {
            int s = colsrc[p];
            uint4 kv = KV4[(size_t)s * 64 + lane];
            float f0 = __uint_as_float(kv.x << 16);
            float f1 = __uint_as_float(kv.x & 0xffff0000u);
            float f2 = __uint_as_float(kv.y << 16);
            float f3 = __uint_as_float(kv.y & 0xffff0000u);
            float f4 = __uint_as_float(kv.z << 16);
            float f5 = __uint_as_float(kv.z & 0xffff0000u);
            float f6 = __uint_as_float(kv.w << 16);
            float f7 = __uint_as_float(kv.w & 0xffff0000u);
            // K-half lanes: partial q.k over own 8 channels; butterfly over
            // the 4-lane head group (xor 1,2 stays within each half).
            float t = q[0] * f0 + q[1] * f1 + q[2] * f2 + q[3] * f3
                    + q[4] * f4 + q[5] * f5 + q[6] * f6 + q[7] * f7;
            t += __shfl_xor(t, 1, 64);
            t += __shfl_xor(t, 2, 64);
            // everyone fetches their head's logit from K lane j (<32)
            float lg = __shfl(t, j, 64) * 0.17677669529663689f; // 1/sqrt(32)
            float mn = fmaxf(m, lg);
            float c1 = expf(m - mn);
            float wg = expf(lg - mn);
            l = l * c1 + wg;
            acc[0] = fmaf(acc[0], c1, wg * f0);
            acc[1] = fmaf(acc[1], c1, wg * f1);
            acc[2] = fmaf(acc[2], c1, wg * f2);
            acc[3] = fmaf(acc[3], c1, wg * f3);
            acc[4] = fmaf(acc[4], c1, wg * f4);
            acc[5] = fmaf(acc[5], c1, wg * f5);
            acc[6] = fmaf(acc[6], c1, wg * f6);
            acc[7] = fmaf(acc[7], c1, wg * f7);
            m = mn;
        }
    }
    float inv = (l > 0.f) ? 1.f / l : 0.f;
    if (lane >= 32) {
#pragma unroll
        for (int i = 0; i < 8; ++i) os[w][j * 8 + i] = acc[i] * inv;
    }
    __syncthreads();
    if (act && lane < 32) {
        int c = lane;
        float a2 = WCBl[1024 + c];                 // bc
#pragma unroll 4
        for (int k = 0; k < 32; ++k) a2 = fmaf(hh[w][k], WCBl[k * D32 + c], a2);
#pragma unroll 8
        for (int k = 0; k < 256; ++k) a2 = fmaf(os[w][k], Wh[k * D32 + c], a2);
        H[(size_t)d * D32 + c] = a2;
    }
}

// --- 32->32 matmul (no bias): O = X @ W ------------------------------------
__global__ __launch_bounds__(256) void k_h32_to_32(
    const float* __restrict__ X, const float* __restrict__ W,
    float* __restrict__ O, int N)
{
    __shared__ float xs[8][33];
    __shared__ float ws[D32 * D32];
    int row0 = blockIdx.x * 8;
    int c = threadIdx.x & 31, lr = threadIdx.x >> 5;
    for (int i = threadIdx.x; i < D32 * D32; i += 256) ws[i] = W[i];
    {
        int gr = row0 + lr;
        xs[lr][c] = (gr < N) ? X[(size_t)gr * D32 + c] : 0.f;
    }
    __syncthreads();
    int row = row0 + lr;
    if (row >= N) return;
    float acc = 0.f;
#pragma unroll
    for (int k = 0; k < D32; ++k) acc = fmaf(xs[lr][k], ws[k * D32 + c], acc);
    O[(size_t)row * D32 + c] = acc;
}

// --- GCN gather (CSR, no atomics) ------------------------------------------
__global__ __launch_bounds__(256) void k_gcn(
    const float* __restrict__ XW, const float* __restrict__ DIS,
    const int* __restrict__ rowptr, const int* __restrict__ colsrc,
    const float* __restrict__ b, float* __restrict__ Out, int N)
{
    int g = threadIdx.x >> 5;
    int c = threadIdx.x & 31;
    int d = blockIdx.x * 8 + g;
    if (d >= N) return;
    float dd = DIS[d];
    float acc = dd * XW[(size_t)d * D32 + c];
    int p1 = rowptr[d + 1];
    for (int p = rowptr[d]; p < p1; ++p) {
        int s = colsrc[p];
        acc += DIS[s] * XW[(size_t)s * D32 + c];
    }
    Out[(size_t)d * D32 + c] = dd * acc + b[c];
}

// ---------------------------------------------------------------------------
extern "C" void kernel_launch(void* const* d_in, const int* in_sizes, int n_in,
                              void* d_out, int out_size, void* d_ws, size_t ws_size,
                              hipStream_t stream)
{
    const float* x  = (const float*)d_in[0];
    const int*   ei = (const int*)d_in[1];
    const int N = in_sizes[0] / INCH;
    const int E = in_sizes[1] / 2;
    const int* src = ei;
    const int* dst = ei + E;

    const float* W_embed = (const float*)d_in[2];
    const float* b_embed = (const float*)d_in[3];
    const float* Wg3 = (const float*)d_in[24];
    const float* bg3 = (const float*)d_in[25];
    const float* Wg4 = (const float*)d_in[26];
    const float* bg4 = (const float*)d_in[27];

    // workspace layout
    unsigned short* KV = (unsigned short*)d_ws;        // N*512 bf16 (51.2MB)
    float* H      = (float*)(KV + (size_t)N * 512);    // N*32
    float* A      = H + (size_t)N * D32;               // N*32 (GCN xw)
    float* B      = A + (size_t)N * D32;               // N*32 (GCN out1)
    int*   rowptr = (int*)(B + (size_t)N * D32);       // N+1
    int*   colsrc = rowptr + (N + 1);                  // E
    int*   cursor = colsrc + E;                        // N
    int*   partials = cursor + N;                      // 256
    float* DIS    = (float*)(partials + 256);          // N
    float* WCB    = DIS + N;                           // 2*1056
    float* out    = (float*)d_out;

    const int nb8 = (N + 7) / 8;
    const int nbN = (N + 255) / 256;
    const int nbE = (E + 255) / 256;

    k_embed<<<nb8, 256, 0, stream>>>(x, W_embed, b_embed, H, N);

    // CSR build (dst-grouped)
    k_zero_i<<<nbN, 256, 0, stream>>>(cursor, N);
    k_count<<<nbE, 256, 0, stream>>>(dst, cursor, E);
    k_scan1<<<nbN, 256, 0, stream>>>(cursor, rowptr, partials, N);
    k_scan2<<<1, 256, 0, stream>>>(partials, nbN);
    k_scan3<<<nbN, 256, 0, stream>>>(rowptr, partials, N);
    k_setcur<<<nbN, 256, 0, stream>>>(rowptr, cursor, N);
    k_fill<<<nbE, 256, 0, stream>>>(src, dst, cursor, colsrc, E);
    k_disk<<<nbN, 256, 0, stream>>>(rowptr, DIS, N);

    k_compose2<<<2, 256, 0, stream>>>(
        (const float*)d_in[10], (const float*)d_in[11],
        (const float*)d_in[12], (const float*)d_in[13],
        (const float*)d_in[20], (const float*)d_in[21],
        (const float*)d_in[22], (const float*)d_in[23], WCB);

    for (int layer = 0; layer < 2; ++layer) {
        int base = 4 + layer * 10;
        const float* Wq = (const float*)d_in[base + 0];
        const float* bq = (const float*)d_in[base + 1];
        const float* Wk = (const float*)d_in[base + 2];
        const float* bk = (const float*)d_in[base + 3];
        const float* Wv = (const float*)d_in[base + 4];
        const float* bv = (const float*)d_in[base + 5];
        const float* Wh = (const float*)d_in[base + 8];

        k_h32_to_kv<<<nb8, 256, 0, stream>>>(H, Wk, bk, Wv, bv, KV, N);
        k_attn<<<(N + 3) / 4, 256, 0, stream>>>(
            (const uint4*)KV, H, rowptr, colsrc,
            (const float4*)Wq, (const float4*)bq, Wh, WCB + layer * 1056, N);
    }

    // GCN layer 1: XW = H@Wg3 -> A ; out -> B
    k_h32_to_32<<<nb8, 256, 0, stream>>>(H, Wg3, A, N);
    k_gcn<<<nb8, 256, 0, stream>>>(A, DIS, rowptr, colsrc, bg3, B, N);
    // GCN layer 2: XW = B@Wg4 -> A ; out -> d_out
    k_h32_to_32<<<nb8, 256, 0, stream>>>(B, Wg4, A, N);
    k_gcn<<<nb8, 256, 0, stream>>>(A, DIS, rowptr, colsrc, bg4, out, N);
}

// Round 4
// 634.684 us; speedup vs baseline: 5.3929x; 1.1087x over previous
//
#include <hip/hip_runtime.h>
#include <cstddef>

// ---------------------------------------------------------------------------
// GNN forward: embed+posenc -> 2x TransformerConv(8 heads x 32) -> 2x GCNConv
// N=50000, E=400000, IN=63, D=32, HC=256.
// R4: bf16 KV rows interleaved per-head [32K|32V]; wave-per-node attn with
// 2-deep register prefetch (MLP) and static-xor-only shuffles; CSR, no atomics.
// ---------------------------------------------------------------------------

#define NH 8
#define HCH 256
#define D32 32
#define INCH 63

__device__ __forceinline__ unsigned short f2bf(float f) {
    unsigned u = __float_as_uint(f);
    u += 0x7fff + ((u >> 16) & 1);   // RNE
    return (unsigned short)(u >> 16);
}

// inv_freq[j] = 10000^(-2j/32) = 10^(-j/4)
__device__ const float c_invf[16] = {
    1.0f, 0.5623413251903491f, 0.31622776601683794f, 0.17782794100389228f,
    0.1f, 0.05623413251903491f, 0.031622776601683791f, 0.017782794100389228f,
    0.01f, 0.005623413251903491f, 0.0031622776601683794f, 0.0017782794100389228f,
    0.001f, 0.0005623413251903491f, 0.00031622776601683794f, 0.00017782794100389227f
};

// --- embed: H[N,32] = x[N,63] @ W[63,32] + b + posenc ----------------------
__global__ __launch_bounds__(256) void k_embed(
    const float* __restrict__ x, const float* __restrict__ W,
    const float* __restrict__ b, float* __restrict__ H, int N)
{
    __shared__ float xs[8][64];
    __shared__ float ws[INCH * D32];
    int row0 = blockIdx.x * 8;
    for (int i = threadIdx.x; i < INCH * D32; i += 256) ws[i] = W[i];
    for (int i = threadIdx.x; i < 8 * INCH; i += 256) {
        int r = i / INCH, cc = i % INCH;
        int gr = row0 + r;
        xs[r][cc] = (gr < N) ? x[(size_t)gr * INCH + cc] : 0.f;
    }
    __syncthreads();
    int lr = threadIdx.x >> 5, c = threadIdx.x & 31;
    int row = row0 + lr;
    if (row >= N) return;
    float acc = b[c];
#pragma unroll
    for (int k = 0; k < INCH; ++k) acc = fmaf(xs[lr][k], ws[k * D32 + c], acc);
    float phase = (float)row * c_invf[c >> 1];
    float pe = (c & 1) ? cosf(phase) : sinf(phase);
    H[(size_t)row * D32 + c] = acc + pe;
}

// --- CSR build -------------------------------------------------------------
__global__ void k_zero_i(int* __restrict__ p, int n) {
    int i = blockIdx.x * 256 + threadIdx.x;
    if (i < n) p[i] = 0;
}
__global__ void k_count(const int* __restrict__ dst, int* __restrict__ cnt, int E) {
    int i = blockIdx.x * 256 + threadIdx.x;
    if (i < E) atomicAdd(&cnt[dst[i]], 1);
}
__global__ void k_scan1(const int* __restrict__ cnt, int* __restrict__ rowptr,
                        int* __restrict__ partials, int N)
{
    __shared__ int s[256];
    int g = blockIdx.x * 256 + threadIdx.x;
    s[threadIdx.x] = (g < N) ? cnt[g] : 0;
    __syncthreads();
    for (int off = 1; off < 256; off <<= 1) {
        int t = (threadIdx.x >= off) ? s[threadIdx.x - off] : 0;
        __syncthreads();
        s[threadIdx.x] += t;
        __syncthreads();
    }
    if (g < N) rowptr[g + 1] = s[threadIdx.x];
    if (threadIdx.x == 255) partials[blockIdx.x] = s[255];
}
__global__ void k_scan2(int* __restrict__ partials, int nb) {
    __shared__ int s[256];
    int t = threadIdx.x;
    s[t] = (t < nb) ? partials[t] : 0;
    __syncthreads();
    for (int off = 1; off < 256; off <<= 1) {
        int v = (t >= off) ? s[t - off] : 0;
        __syncthreads();
        s[t] += v;
        __syncthreads();
    }
    partials[t] = (t == 0) ? 0 : s[t - 1];  // exclusive
}
__global__ void k_scan3(int* __restrict__ rowptr, const int* __restrict__ partials, int N) {
    int g = blockIdx.x * 256 + threadIdx.x;
    if (g < N) rowptr[g + 1] += partials[blockIdx.x];
    if (g == 0) rowptr[0] = 0;
}
__global__ void k_setcur(const int* __restrict__ rowptr, int* __restrict__ cur, int N) {
    int i = blockIdx.x * 256 + threadIdx.x;
    if (i < N) cur[i] = rowptr[i];
}
__global__ void k_fill(const int* __restrict__ src, const int* __restrict__ dst,
                       int* __restrict__ cur, int* __restrict__ colsrc, int E)
{
    int e = blockIdx.x * 256 + threadIdx.x;
    if (e < E) {
        int p = atomicAdd(&cur[dst[e]], 1);
        colsrc[p] = src[e];
    }
}
__global__ void k_disk(const int* __restrict__ rowptr, float* __restrict__ DIS, int N) {
    int i = blockIdx.x * 256 + threadIdx.x;
    if (i < N) DIS[i] = rsqrtf((float)(rowptr[i + 1] - rowptr[i]) + 1.0f);
}

// --- compose skip for BOTH layers: Wc = Ws@Wh (32x32), bc = bs@Wh + bh -----
__global__ void k_compose2(
    const float* __restrict__ Wsk1, const float* __restrict__ bsk1,
    const float* __restrict__ Wh1,  const float* __restrict__ bh1,
    const float* __restrict__ Wsk2, const float* __restrict__ bsk2,
    const float* __restrict__ Wh2,  const float* __restrict__ bh2,
    float* __restrict__ WCB)
{
    const float* Wsk = blockIdx.x ? Wsk2 : Wsk1;
    const float* bsk = blockIdx.x ? bsk2 : bsk1;
    const float* Wh  = blockIdx.x ? Wh2  : Wh1;
    const float* bh  = blockIdx.x ? bh2  : bh1;
    float* o = WCB + blockIdx.x * 1056;
    for (int i = threadIdx.x; i < D32 * D32 + D32; i += 256) {
        if (i < D32 * D32) {
            int r = i >> 5, c = i & 31;
            float a = 0.f;
            for (int k = 0; k < HCH; ++k) a = fmaf(Wsk[r * HCH + k], Wh[k * D32 + c], a);
            o[i] = a;
        } else {
            int c = i - D32 * D32;
            float a = bh[c];
            for (int k = 0; k < HCH; ++k) a = fmaf(bsk[k], Wh[k * D32 + c], a);
            o[1024 + c] = a;
        }
    }
}

// --- K & V projections -> bf16 rows, per-head [32 K | 32 V] ----------------
// element pos within 512-row: K(h,cc) -> h*64+cc ; V(h,cc) -> h*64+32+cc
__global__ __launch_bounds__(256) void k_h32_to_kv(
    const float* __restrict__ Hm,
    const float* __restrict__ W1, const float* __restrict__ b1,
    const float* __restrict__ W2, const float* __restrict__ b2,
    unsigned short* __restrict__ KV, int N)
{
    __shared__ float hs[8][33];
    int row0 = blockIdx.x * 8;
    int c = threadIdx.x;
    {
        int r = threadIdx.x >> 5, k = threadIdx.x & 31;
        int gr = row0 + r;
        hs[r][k] = (gr < N) ? Hm[(size_t)gr * D32 + k] : 0.f;
    }
    __syncthreads();
    float a1[8], a2[8];
    float bb1 = b1[c], bb2 = b2[c];
#pragma unroll
    for (int r = 0; r < 8; ++r) { a1[r] = bb1; a2[r] = bb2; }
#pragma unroll 8
    for (int k = 0; k < 32; ++k) {
        float w1 = W1[k * HCH + c], w2 = W2[k * HCH + c];
#pragma unroll
        for (int r = 0; r < 8; ++r) {
            float h = hs[r][k];
            a1[r] = fmaf(h, w1, a1[r]);
            a2[r] = fmaf(h, w2, a2[r]);
        }
    }
    int hh = c >> 5, cc = c & 31;
#pragma unroll
    for (int r = 0; r < 8; ++r) {
        int gr = row0 + r;
        if (gr < N) {
            KV[(size_t)gr * 512 + hh * 64 + cc]      = f2bf(a1[r]);
            KV[(size_t)gr * 512 + hh * 64 + 32 + cc] = f2bf(a2[r]);
        }
    }
}

// --- fused attention: wave per dst node, bf16 KV, 2-deep prefetch ----------
// lane l = 8h+sub: sub<4 -> K channels h*32+sub*8..+7 ; sub>=4 -> same V chans
__global__ __launch_bounds__(256) void k_attn(
    const uint4* __restrict__ KV4, float* H,
    const int* __restrict__ rowptr, const int* __restrict__ colsrc,
    const float4* __restrict__ Wq4, const float4* __restrict__ bq4,
    const float* __restrict__ Wh, const float* __restrict__ WCBl, int N)
{
    __shared__ float hh[4][32];
    __shared__ float os[4][264];
    int w = threadIdx.x >> 6, lane = threadIdx.x & 63;
    int d = blockIdx.x * 4 + w;
    bool act = d < N;
    if (act && lane < 32) hh[w][lane] = H[(size_t)d * D32 + lane];
    __syncthreads();

    int h = lane >> 3, subk = lane & 3;
    int jq = h * 8 + subk * 2;        // float4 index: q channels h*32+subk*8..+7
    float q[8];
    {
        float4 b0 = bq4[jq], b1 = bq4[jq + 1];
        q[0] = b0.x; q[1] = b0.y; q[2] = b0.z; q[3] = b0.w;
        q[4] = b1.x; q[5] = b1.y; q[6] = b1.z; q[7] = b1.w;
        if (act) {
#pragma unroll 4
            for (int k = 0; k < 32; ++k) {
                float hv = hh[w][k];
                float4 w0 = Wq4[k * 64 + jq], w1 = Wq4[k * 64 + jq + 1];
                q[0] = fmaf(hv, w0.x, q[0]); q[1] = fmaf(hv, w0.y, q[1]);
                q[2] = fmaf(hv, w0.z, q[2]); q[3] = fmaf(hv, w0.w, q[3]);
                q[4] = fmaf(hv, w1.x, q[4]); q[5] = fmaf(hv, w1.y, q[5]);
                q[6] = fmaf(hv, w1.z, q[6]); q[7] = fmaf(hv, w1.w, q[7]);
            }
        }
    }

    float m = -INFINITY, l = 0.f;
    float acc[8] = {0.f, 0.f, 0.f, 0.f, 0.f, 0.f, 0.f, 0.f};
    if (act) {
        int p0 = rowptr[d], p1 = rowptr[d + 1];
        if (p1 > p0) {
            // 2-deep software pipeline: kvA = current, kvB = next
            int pB = (p0 + 1 < p1) ? p0 + 1 : p1 - 1;
            int sA = colsrc[p0], sB = colsrc[pB];
            uint4 kvA = KV4[(size_t)sA * 64 + lane];
            uint4 kvB = KV4[(size_t)sB * 64 + lane];
            for (int p = p0; p < p1; ++p) {
                int pn = (p + 2 < p1) ? p + 2 : p1 - 1;
                int sN = colsrc[pn];
                uint4 kvN = KV4[(size_t)sN * 64 + lane];   // issued before use of kvA
                float f0 = __uint_as_float(kvA.x << 16);
                float f1 = __uint_as_float(kvA.x & 0xffff0000u);
                float f2 = __uint_as_float(kvA.y << 16);
                float f3 = __uint_as_float(kvA.y & 0xffff0000u);
                float f4 = __uint_as_float(kvA.z << 16);
                float f5 = __uint_as_float(kvA.z & 0xffff0000u);
                float f6 = __uint_as_float(kvA.w << 16);
                float f7 = __uint_as_float(kvA.w & 0xffff0000u);
                float t = q[0] * f0 + q[1] * f1 + q[2] * f2 + q[3] * f3
                        + q[4] * f4 + q[5] * f5 + q[6] * f6 + q[7] * f7;
                t += __shfl_xor(t, 1, 64);
                t += __shfl_xor(t, 2, 64);          // K-quad has head logit
                float lg = __shfl_xor(t, 4, 64) * 0.17677669529663689f; // ->V quad
                float mn = fmaxf(m, lg);
                float c1 = __expf(m - mn);
                float wg = __expf(lg - mn);
                l = l * c1 + wg;
                acc[0] = fmaf(acc[0], c1, wg * f0);
                acc[1] = fmaf(acc[1], c1, wg * f1);
                acc[2] = fmaf(acc[2], c1, wg * f2);
                acc[3] = fmaf(acc[3], c1, wg * f3);
                acc[4] = fmaf(acc[4], c1, wg * f4);
                acc[5] = fmaf(acc[5], c1, wg * f5);
                acc[6] = fmaf(acc[6], c1, wg * f6);
                acc[7] = fmaf(acc[7], c1, wg * f7);
                m = mn;
                kvA = kvB; kvB = kvN;
            }
        }
    }
    // V lanes (sub>=4) hold the attention output for channels h*32+subk*8..+7
    float inv = (l > 0.f) ? 1.f / l : 0.f;
    if ((lane & 4) != 0) {
        int g = h * 32 + subk * 8;
#pragma unroll
        for (int i = 0; i < 8; ++i) os[w][g + i] = acc[i] * inv;
    }
    __syncthreads();

    if (act) {
        int c = lane & 31, half = lane >> 5;
        float a2 = 0.f;
        if (half == 0) {
            a2 = WCBl[1024 + c];               // bc
#pragma unroll 4
            for (int k = 0; k < 32; ++k) a2 = fmaf(hh[w][k], WCBl[k * D32 + c], a2);
        }
        int kb = half * 128;
#pragma unroll 8
        for (int kk = 0; kk < 128; ++kk)
            a2 = fmaf(os[w][kb + kk], Wh[(kb + kk) * D32 + c], a2);
        a2 += __shfl_xor(a2, 32, 64);
        if (lane < 32) H[(size_t)d * D32 + c] = a2;
    }
}

// --- 32->32 matmul (no bias): O = X @ W ------------------------------------
__global__ __launch_bounds__(256) void k_h32_to_32(
    const float* __restrict__ X, const float* __restrict__ W,
    float* __restrict__ O, int N)
{
    __shared__ float xs[8][33];
    __shared__ float ws[D32 * D32];
    int row0 = blockIdx.x * 8;
    int c = threadIdx.x & 31, lr = threadIdx.x >> 5;
    for (int i = threadIdx.x; i < D32 * D32; i += 256) ws[i] = W[i];
    {
        int gr = row0 + lr;
        xs[lr][c] = (gr < N) ? X[(size_t)gr * D32 + c] : 0.f;
    }
    __syncthreads();
    int row = row0 + lr;
    if (row >= N) return;
    float acc = 0.f;
#pragma unroll
    for (int k = 0; k < D32; ++k) acc = fmaf(xs[lr][k], ws[k * D32 + c], acc);
    O[(size_t)row * D32 + c] = acc;
}

// --- GCN gather (CSR, no atomics) ------------------------------------------
__global__ __launch_bounds__(256) void k_gcn(
    const float* __restrict__ XW, const float* __restrict__ DIS,
    const int* __restrict__ rowptr, const int* __restrict__ colsrc,
    const float* __restrict__ b, float* __restrict__ Out, int N)
{
    int g = threadIdx.x >> 5;
    int c = threadIdx.x & 31;
    int d = blockIdx.x * 8 + g;
    if (d >= N) return;
    float dd = DIS[d];
    float acc = dd * XW[(size_t)d * D32 + c];
    int p1 = rowptr[d + 1];
    for (int p = rowptr[d]; p < p1; ++p) {
        int s = colsrc[p];
        acc += DIS[s] * XW[(size_t)s * D32 + c];
    }
    Out[(size_t)d * D32 + c] = dd * acc + b[c];
}

// ---------------------------------------------------------------------------
extern "C" void kernel_launch(void* const* d_in, const int* in_sizes, int n_in,
                              void* d_out, int out_size, void* d_ws, size_t ws_size,
                              hipStream_t stream)
{
    const float* x  = (const float*)d_in[0];
    const int*   ei = (const int*)d_in[1];
    const int N = in_sizes[0] / INCH;
    const int E = in_sizes[1] / 2;
    const int* src = ei;
    const int* dst = ei + E;

    const float* W_embed = (const float*)d_in[2];
    const float* b_embed = (const float*)d_in[3];
    const float* Wg3 = (const float*)d_in[24];
    const float* bg3 = (const float*)d_in[25];
    const float* Wg4 = (const float*)d_in[26];
    const float* bg4 = (const float*)d_in[27];

    unsigned short* KV = (unsigned short*)d_ws;        // N*512 bf16
    float* H      = (float*)(KV + (size_t)N * 512);    // N*32
    float* A      = H + (size_t)N * D32;               // N*32
    float* B      = A + (size_t)N * D32;               // N*32
    int*   rowptr = (int*)(B + (size_t)N * D32);       // N+1
    int*   colsrc = rowptr + (N + 1);                  // E
    int*   cursor = colsrc + E;                        // N
    int*   partials = cursor + N;                      // 256
    float* DIS    = (float*)(partials + 256);          // N
    float* WCB    = DIS + N;                           // 2*1056
    float* out    = (float*)d_out;

    const int nb8 = (N + 7) / 8;
    const int nbN = (N + 255) / 256;
    const int nbE = (E + 255) / 256;

    k_embed<<<nb8, 256, 0, stream>>>(x, W_embed, b_embed, H, N);

    k_zero_i<<<nbN, 256, 0, stream>>>(cursor, N);
    k_count<<<nbE, 256, 0, stream>>>(dst, cursor, E);
    k_scan1<<<nbN, 256, 0, stream>>>(cursor, rowptr, partials, N);
    k_scan2<<<1, 256, 0, stream>>>(partials, nbN);
    k_scan3<<<nbN, 256, 0, stream>>>(rowptr, partials, N);
    k_setcur<<<nbN, 256, 0, stream>>>(rowptr, cursor, N);
    k_fill<<<nbE, 256, 0, stream>>>(src, dst, cursor, colsrc, E);
    k_disk<<<nbN, 256, 0, stream>>>(rowptr, DIS, N);

    k_compose2<<<2, 256, 0, stream>>>(
        (const float*)d_in[10], (const float*)d_in[11],
        (const float*)d_in[12], (const float*)d_in[13],
        (const float*)d_in[20], (const float*)d_in[21],
        (const float*)d_in[22], (const float*)d_in[23], WCB);

    for (int layer = 0; layer < 2; ++layer) {
        int base = 4 + layer * 10;
        const float* Wq = (const float*)d_in[base + 0];
        const float* bq = (const float*)d_in[base + 1];
        const float* Wk = (const float*)d_in[base + 2];
        const float* bk = (const float*)d_in[base + 3];
        const float* Wv = (const float*)d_in[base + 4];
        const float* bv = (const float*)d_in[base + 5];
        const float* Wh = (const float*)d_in[base + 8];

        k_h32_to_kv<<<nb8, 256, 0, stream>>>(H, Wk, bk, Wv, bv, KV, N);
        k_attn<<<(N + 3) / 4, 256, 0, stream>>>(
            (const uint4*)KV, H, rowptr, colsrc,
            (const float4*)Wq, (const float4*)bq, Wh, WCB + layer * 1056, N);
    }

    k_h32_to_32<<<nb8, 256, 0, stream>>>(H, Wg3, A, N);
    k_gcn<<<nb8, 256, 0, stream>>>(A, DIS, rowptr, colsrc, bg3, B, N);
    k_h32_to_32<<<nb8, 256, 0, stream>>>(B, Wg4, A, N);
    k_gcn<<<nb8, 256, 0, stream>>>(A, DIS, rowptr, colsrc, bg4, out, N);
}

// Round 5
// 501.090 us; speedup vs baseline: 6.8307x; 1.2666x over previous
//
#include <hip/hip_runtime.h>
#include <cstddef>

// ---------------------------------------------------------------------------
// GNN forward: embed+posenc -> 2x TransformerConv(8 heads x 32) -> 2x GCNConv
// N=50000, E=400000, IN=63, D=32, HC=256.
// R5: no-max softmax (logits bounded ~1 -> shift-invariant exact), Q pre-scaled
// by log2e/sqrt(32) and precomputed with K/V/SKIP in one projection pass;
// attn edge loop = independent accumulate with 4-deep rolling prefetch;
// GCN: DIS folded into XW, depth-4 prefetch. CSR, no per-edge atomics.
// ---------------------------------------------------------------------------

#define NH 8
#define HCH 256
#define D32 32
#define INCH 63
#define CSCALE 0.25503485356f   // log2(e) / sqrt(32)

__device__ __forceinline__ unsigned short f2bf(float f) {
    unsigned u = __float_as_uint(f);
    u += 0x7fff + ((u >> 16) & 1);   // RNE
    return (unsigned short)(u >> 16);
}

// inv_freq[j] = 10000^(-2j/32) = 10^(-j/4)
__device__ const float c_invf[16] = {
    1.0f, 0.5623413251903491f, 0.31622776601683794f, 0.17782794100389228f,
    0.1f, 0.05623413251903491f, 0.031622776601683791f, 0.017782794100389228f,
    0.01f, 0.005623413251903491f, 0.0031622776601683794f, 0.0017782794100389228f,
    0.001f, 0.0005623413251903491f, 0.00031622776601683794f, 0.00017782794100389227f
};

// --- embed: H[N,32] = x[N,63] @ W[63,32] + b + posenc ----------------------
__global__ __launch_bounds__(256) void k_embed(
    const float* __restrict__ x, const float* __restrict__ W,
    const float* __restrict__ b, float* __restrict__ H, int N)
{
    __shared__ float xs[8][64];
    __shared__ float ws[INCH * D32];
    int row0 = blockIdx.x * 8;
    for (int i = threadIdx.x; i < INCH * D32; i += 256) ws[i] = W[i];
    for (int i = threadIdx.x; i < 8 * INCH; i += 256) {
        int r = i / INCH, cc = i % INCH;
        int gr = row0 + r;
        xs[r][cc] = (gr < N) ? x[(size_t)gr * INCH + cc] : 0.f;
    }
    __syncthreads();
    int lr = threadIdx.x >> 5, c = threadIdx.x & 31;
    int row = row0 + lr;
    if (row >= N) return;
    float acc = b[c];
#pragma unroll
    for (int k = 0; k < INCH; ++k) acc = fmaf(xs[lr][k], ws[k * D32 + c], acc);
    float phase = (float)row * c_invf[c >> 1];
    float pe = (c & 1) ? cosf(phase) : sinf(phase);
    H[(size_t)row * D32 + c] = acc + pe;
}

// --- CSR build -------------------------------------------------------------
__global__ void k_zero_i(int* __restrict__ p, int n) {
    int i = blockIdx.x * 256 + threadIdx.x;
    if (i < n) p[i] = 0;
}
__global__ void k_count(const int* __restrict__ dst, int* __restrict__ cnt, int E) {
    int i = blockIdx.x * 256 + threadIdx.x;
    if (i < E) atomicAdd(&cnt[dst[i]], 1);
}
__global__ void k_scan1(const int* __restrict__ cnt, int* __restrict__ rowptr,
                        int* __restrict__ partials, int N)
{
    __shared__ int s[256];
    int g = blockIdx.x * 256 + threadIdx.x;
    s[threadIdx.x] = (g < N) ? cnt[g] : 0;
    __syncthreads();
    for (int off = 1; off < 256; off <<= 1) {
        int t = (threadIdx.x >= off) ? s[threadIdx.x - off] : 0;
        __syncthreads();
        s[threadIdx.x] += t;
        __syncthreads();
    }
    if (g < N) rowptr[g + 1] = s[threadIdx.x];
    if (threadIdx.x == 255) partials[blockIdx.x] = s[255];
}
__global__ void k_scan2(int* __restrict__ partials, int nb) {
    __shared__ int s[256];
    int t = threadIdx.x;
    s[t] = (t < nb) ? partials[t] : 0;
    __syncthreads();
    for (int off = 1; off < 256; off <<= 1) {
        int v = (t >= off) ? s[t - off] : 0;
        __syncthreads();
        s[t] += v;
        __syncthreads();
    }
    partials[t] = (t == 0) ? 0 : s[t - 1];  // exclusive
}
__global__ void k_scan3(int* __restrict__ rowptr, const int* __restrict__ partials, int N) {
    int g = blockIdx.x * 256 + threadIdx.x;
    if (g < N) rowptr[g + 1] += partials[blockIdx.x];
    if (g == 0) rowptr[0] = 0;
}
__global__ void k_setcur(const int* __restrict__ rowptr, int* __restrict__ cur, int N) {
    int i = blockIdx.x * 256 + threadIdx.x;
    if (i < N) cur[i] = rowptr[i];
}
__global__ void k_fill(const int* __restrict__ src, const int* __restrict__ dst,
                       int* __restrict__ cur, int* __restrict__ colsrc, int E)
{
    int e = blockIdx.x * 256 + threadIdx.x;
    if (e < E) {
        int p = atomicAdd(&cur[dst[e]], 1);
        colsrc[p] = src[e];
    }
}
__global__ void k_disk(const int* __restrict__ rowptr, float* __restrict__ DIS, int N) {
    int i = blockIdx.x * 256 + threadIdx.x;
    if (i < N) DIS[i] = rsqrtf((float)(rowptr[i + 1] - rowptr[i]) + 1.0f);
}

// --- compose skip for BOTH layers: Wc = Ws@Wh (32x32), bc = bs@Wh + bh -----
__global__ void k_compose2(
    const float* __restrict__ Wsk1, const float* __restrict__ bsk1,
    const float* __restrict__ Wh1,  const float* __restrict__ bh1,
    const float* __restrict__ Wsk2, const float* __restrict__ bsk2,
    const float* __restrict__ Wh2,  const float* __restrict__ bh2,
    float* __restrict__ WCB)
{
    const float* Wsk = blockIdx.x ? Wsk2 : Wsk1;
    const float* bsk = blockIdx.x ? bsk2 : bsk1;
    const float* Wh  = blockIdx.x ? Wh2  : Wh1;
    const float* bh  = blockIdx.x ? bh2  : bh1;
    float* o = WCB + blockIdx.x * 1056;
    for (int i = threadIdx.x; i < D32 * D32 + D32; i += 256) {
        if (i < D32 * D32) {
            int r = i >> 5, c = i & 31;
            float a = 0.f;
            for (int k = 0; k < HCH; ++k) a = fmaf(Wsk[r * HCH + k], Wh[k * D32 + c], a);
            o[i] = a;
        } else {
            int c = i - D32 * D32;
            float a = bh[c];
            for (int k = 0; k < HCH; ++k) a = fmaf(bsk[k], Wh[k * D32 + c], a);
            o[1024 + c] = a;
        }
    }
}

// --- Q (fp32, pre-scaled), K/V (bf16 per-head [32K|32V]), SKIP=H@Wc+bc -----
__global__ __launch_bounds__(256) void k_h32_to_kvqs(
    const float* __restrict__ Hm,
    const float* __restrict__ Wq, const float* __restrict__ bq,
    const float* __restrict__ Wk, const float* __restrict__ bk,
    const float* __restrict__ Wv, const float* __restrict__ bv,
    const float* __restrict__ WCBl,
    float* __restrict__ Q, unsigned short* __restrict__ KV,
    float* __restrict__ SKIP, int N)
{
    __shared__ float hs[8][33];
    int row0 = blockIdx.x * 8;
    int c = threadIdx.x;
    {
        int r = threadIdx.x >> 5, k = threadIdx.x & 31;
        int gr = row0 + r;
        hs[r][k] = (gr < N) ? Hm[(size_t)gr * D32 + k] : 0.f;
    }
    __syncthreads();
    float aQ[8], aK[8], aV[8], aS[8];
    float bQ = bq[c], bK = bk[c], bV = bv[c];
    float bS = (c < 32) ? WCBl[1024 + c] : 0.f;
#pragma unroll
    for (int r = 0; r < 8; ++r) { aQ[r] = bQ; aK[r] = bK; aV[r] = bV; aS[r] = bS; }
#pragma unroll 8
    for (int k = 0; k < 32; ++k) {
        float wq = Wq[k * HCH + c], wk = Wk[k * HCH + c], wv = Wv[k * HCH + c];
        float wc = (c < 32) ? WCBl[k * D32 + c] : 0.f;
#pragma unroll
        for (int r = 0; r < 8; ++r) {
            float h = hs[r][k];
            aQ[r] = fmaf(h, wq, aQ[r]);
            aK[r] = fmaf(h, wk, aK[r]);
            aV[r] = fmaf(h, wv, aV[r]);
            aS[r] = fmaf(h, wc, aS[r]);
        }
    }
    int hh = c >> 5, cc = c & 31;
#pragma unroll
    for (int r = 0; r < 8; ++r) {
        int gr = row0 + r;
        if (gr < N) {
            Q[(size_t)gr * HCH + c] = aQ[r] * CSCALE;
            KV[(size_t)gr * 512 + hh * 64 + cc]      = f2bf(aK[r]);
            KV[(size_t)gr * 512 + hh * 64 + 32 + cc] = f2bf(aV[r]);
            if (c < 32) SKIP[(size_t)gr * D32 + c] = aS[r];
        }
    }
}

// --- fused attention: wave per dst node, no-max softmax, 4-deep prefetch ---
// lane l = 8h+sub: sub<4 -> K channels h*32+sub*8..+7 ; sub>=4 -> same V chans
__global__ __launch_bounds__(256) void k_attn(
    const uint4* __restrict__ KV4, const float4* __restrict__ Q4,
    const float* __restrict__ SKIP, float* __restrict__ H,
    const int* __restrict__ rowptr, const int* __restrict__ colsrc,
    const float* __restrict__ Wh, int N)
{
    __shared__ float os[4][264];
    int w = threadIdx.x >> 6, lane = threadIdx.x & 63;
    int d = blockIdx.x * 4 + w;
    bool act = d < N;
    int h = lane >> 3, subk = lane & 3;
    int jq = h * 8 + subk * 2;

    float q[8] = {0.f, 0.f, 0.f, 0.f, 0.f, 0.f, 0.f, 0.f};
    if (act) {
        float4 q0 = Q4[(size_t)d * 64 + jq];
        float4 q1 = Q4[(size_t)d * 64 + jq + 1];
        q[0] = q0.x; q[1] = q0.y; q[2] = q0.z; q[3] = q0.w;
        q[4] = q1.x; q[5] = q1.y; q[6] = q1.z; q[7] = q1.w;
    }

    float l = 0.f;
    float acc[8] = {0.f, 0.f, 0.f, 0.f, 0.f, 0.f, 0.f, 0.f};
    if (act) {
        int p0 = rowptr[d], p1 = rowptr[d + 1];
        if (p1 > p0) {
            int pl = p1 - 1;
            int sA = colsrc[p0];
            int sB = colsrc[p0 + 1 <= pl ? p0 + 1 : pl];
            int sC = colsrc[p0 + 2 <= pl ? p0 + 2 : pl];
            int sD = colsrc[p0 + 3 <= pl ? p0 + 3 : pl];
            uint4 kvA = KV4[(size_t)sA * 64 + lane];
            uint4 kvB = KV4[(size_t)sB * 64 + lane];
            uint4 kvC = KV4[(size_t)sC * 64 + lane];
            uint4 kvD = KV4[(size_t)sD * 64 + lane];
#pragma unroll 4
            for (int p = p0; p < p1; ++p) {
                int pn = p + 4 <= pl ? p + 4 : pl;
                int sN = colsrc[pn];
                uint4 kvN = KV4[(size_t)sN * 64 + lane];   // in flight over PROC
                float f0 = __uint_as_float(kvA.x << 16);
                float f1 = __uint_as_float(kvA.x & 0xffff0000u);
                float f2 = __uint_as_float(kvA.y << 16);
                float f3 = __uint_as_float(kvA.y & 0xffff0000u);
                float f4 = __uint_as_float(kvA.z << 16);
                float f5 = __uint_as_float(kvA.z & 0xffff0000u);
                float f6 = __uint_as_float(kvA.w << 16);
                float f7 = __uint_as_float(kvA.w & 0xffff0000u);
                float t = q[0] * f0 + q[1] * f1 + q[2] * f2 + q[3] * f3
                        + q[4] * f4 + q[5] * f5 + q[6] * f6 + q[7] * f7;
                t += __shfl_xor(t, 1, 64);
                t += __shfl_xor(t, 2, 64);              // K-quad holds head dot
                float ex = __shfl_xor(t, 4, 64);        // hand to V quad
                float wg = exp2f(ex);                   // Q pre-scaled: ex = lg*log2e/sqrt32
                l += wg;
                acc[0] = fmaf(wg, f0, acc[0]);
                acc[1] = fmaf(wg, f1, acc[1]);
                acc[2] = fmaf(wg, f2, acc[2]);
                acc[3] = fmaf(wg, f3, acc[3]);
                acc[4] = fmaf(wg, f4, acc[4]);
                acc[5] = fmaf(wg, f5, acc[5]);
                acc[6] = fmaf(wg, f6, acc[6]);
                acc[7] = fmaf(wg, f7, acc[7]);
                kvA = kvB; kvB = kvC; kvC = kvD; kvD = kvN;
            }
        }
    }
    float inv = (l > 0.f) ? 1.f / l : 0.f;
    if ((lane & 4) != 0) {
        int g = h * 32 + subk * 8;
#pragma unroll
        for (int i = 0; i < 8; ++i) os[w][g + i] = acc[i] * inv;
    }
    __syncthreads();

    if (act) {
        int c = lane & 31, half = lane >> 5;
        float a2 = half ? 0.f : SKIP[(size_t)d * D32 + c];
        int kb = half * 128;
#pragma unroll 8
        for (int kk = 0; kk < 128; ++kk)
            a2 = fmaf(os[w][kb + kk], Wh[(kb + kk) * D32 + c], a2);
        a2 += __shfl_xor(a2, 32, 64);
        if (lane < 32) H[(size_t)d * D32 + c] = a2;
    }
}

// --- 32->32 matmul, output scaled by DIS[row]: O = DIS[row] * (X @ W) ------
__global__ __launch_bounds__(256) void k_h32_to_32s(
    const float* __restrict__ X, const float* __restrict__ W,
    const float* __restrict__ DIS, float* __restrict__ O, int N)
{
    __shared__ float xs[8][33];
    __shared__ float ws[D32 * D32];
    int row0 = blockIdx.x * 8;
    int c = threadIdx.x & 31, lr = threadIdx.x >> 5;
    for (int i = threadIdx.x; i < D32 * D32; i += 256) ws[i] = W[i];
    {
        int gr = row0 + lr;
        xs[lr][c] = (gr < N) ? X[(size_t)gr * D32 + c] : 0.f;
    }
    __syncthreads();
    int row = row0 + lr;
    if (row >= N) return;
    float acc = 0.f;
#pragma unroll
    for (int k = 0; k < D32; ++k) acc = fmaf(xs[lr][k], ws[k * D32 + c], acc);
    O[(size_t)row * D32 + c] = DIS[row] * acc;
}

// --- GCN gather (CSR): out = DIS[d]*(XWp[d] + sum_s XWp[s]) + b ------------
// XWp already has DIS[row] folded in.
__global__ __launch_bounds__(256) void k_gcn(
    const float* __restrict__ XWp, const float* __restrict__ DIS,
    const int* __restrict__ rowptr, const int* __restrict__ colsrc,
    const float* __restrict__ b, float* __restrict__ Out, int N)
{
    int g = threadIdx.x >> 5;
    int c = threadIdx.x & 31;
    int d = blockIdx.x * 8 + g;
    if (d >= N) return;
    float acc = XWp[(size_t)d * D32 + c];
    int p0 = rowptr[d], p1 = rowptr[d + 1];
    if (p1 > p0) {
        int pl = p1 - 1;
        int sA = colsrc[p0];
        int sB = colsrc[p0 + 1 <= pl ? p0 + 1 : pl];
        int sC = colsrc[p0 + 2 <= pl ? p0 + 2 : pl];
        int sD = colsrc[p0 + 3 <= pl ? p0 + 3 : pl];
        float vA = XWp[(size_t)sA * D32 + c];
        float vB = XWp[(size_t)sB * D32 + c];
        float vC = XWp[(size_t)sC * D32 + c];
        float vD = XWp[(size_t)sD * D32 + c];
#pragma unroll 4
        for (int p = p0; p < p1; ++p) {
            int pn = p + 4 <= pl ? p + 4 : pl;
            int sN = colsrc[pn];
            float vN = XWp[(size_t)sN * D32 + c];
            acc += vA;
            vA = vB; vB = vC; vC = vD; vD = vN;
        }
    }
    Out[(size_t)d * D32 + c] = DIS[d] * acc + b[c];
}

// ---------------------------------------------------------------------------
extern "C" void kernel_launch(void* const* d_in, const int* in_sizes, int n_in,
                              void* d_out, int out_size, void* d_ws, size_t ws_size,
                              hipStream_t stream)
{
    const float* x  = (const float*)d_in[0];
    const int*   ei = (const int*)d_in[1];
    const int N = in_sizes[0] / INCH;
    const int E = in_sizes[1] / 2;
    const int* src = ei;
    const int* dst = ei + E;

    const float* W_embed = (const float*)d_in[2];
    const float* b_embed = (const float*)d_in[3];
    const float* Wg3 = (const float*)d_in[24];
    const float* bg3 = (const float*)d_in[25];
    const float* Wg4 = (const float*)d_in[26];
    const float* bg4 = (const float*)d_in[27];

    unsigned short* KV = (unsigned short*)d_ws;        // N*512 bf16  (51.2MB)
    float* Q      = (float*)(KV + (size_t)N * 512);    // N*256 f32   (51.2MB)
    float* H      = Q + (size_t)N * HCH;               // N*32
    float* A      = H + (size_t)N * D32;               // N*32 (SKIP / XWp)
    float* B      = A + (size_t)N * D32;               // N*32
    int*   rowptr = (int*)(B + (size_t)N * D32);       // N+1
    int*   colsrc = rowptr + (N + 1);                  // E
    int*   cursor = colsrc + E;                        // N
    int*   partials = cursor + N;                      // 256
    float* DIS    = (float*)(partials + 256);          // N
    float* WCB    = DIS + N;                           // 2*1056
    float* out    = (float*)d_out;

    const int nb8 = (N + 7) / 8;
    const int nbN = (N + 255) / 256;
    const int nbE = (E + 255) / 256;

    k_embed<<<nb8, 256, 0, stream>>>(x, W_embed, b_embed, H, N);

    k_zero_i<<<nbN, 256, 0, stream>>>(cursor, N);
    k_count<<<nbE, 256, 0, stream>>>(dst, cursor, E);
    k_scan1<<<nbN, 256, 0, stream>>>(cursor, rowptr, partials, N);
    k_scan2<<<1, 256, 0, stream>>>(partials, nbN);
    k_scan3<<<nbN, 256, 0, stream>>>(rowptr, partials, N);
    k_setcur<<<nbN, 256, 0, stream>>>(rowptr, cursor, N);
    k_fill<<<nbE, 256, 0, stream>>>(src, dst, cursor, colsrc, E);
    k_disk<<<nbN, 256, 0, stream>>>(rowptr, DIS, N);

    k_compose2<<<2, 256, 0, stream>>>(
        (const float*)d_in[10], (const float*)d_in[11],
        (const float*)d_in[12], (const float*)d_in[13],
        (const float*)d_in[20], (const float*)d_in[21],
        (const float*)d_in[22], (const float*)d_in[23], WCB);

    for (int layer = 0; layer < 2; ++layer) {
        int base = 4 + layer * 10;
        const float* Wq = (const float*)d_in[base + 0];
        const float* bq = (const float*)d_in[base + 1];
        const float* Wk = (const float*)d_in[base + 2];
        const float* bk = (const float*)d_in[base + 3];
        const float* Wv = (const float*)d_in[base + 4];
        const float* bv = (const float*)d_in[base + 5];
        const float* Wh = (const float*)d_in[base + 8];

        k_h32_to_kvqs<<<nb8, 256, 0, stream>>>(
            H, Wq, bq, Wk, bk, Wv, bv, WCB + layer * 1056, Q, KV, A, N);
        k_attn<<<(N + 3) / 4, 256, 0, stream>>>(
            (const uint4*)KV, (const float4*)Q, A, H, rowptr, colsrc, Wh, N);
    }

    // GCN layer 1: XWp = DIS*(H@Wg3) -> A ; out -> B
    k_h32_to_32s<<<nb8, 256, 0, stream>>>(H, Wg3, DIS, A, N);
    k_gcn<<<nb8, 256, 0, stream>>>(A, DIS, rowptr, colsrc, bg3, B, N);
    // GCN layer 2: XWp = DIS*(B@Wg4) -> A ; out -> d_out
    k_h32_to_32s<<<nb8, 256, 0, stream>>>(B, Wg4, DIS, A, N);
    k_gcn<<<nb8, 256, 0, stream>>>(A, DIS, rowptr, colsrc, bg4, out, N);
}

// Round 6
// 444.181 us; speedup vs baseline: 7.7059x; 1.1281x over previous
//
#include <hip/hip_runtime.h>
#include <cstddef>

// ---------------------------------------------------------------------------
// GNN forward: embed+posenc -> 2x TransformerConv(8 heads x 32) -> 2x GCNConv
// N=50000, E=400000, IN=63, D=32, HC=256.
// R6: KV row layout = per-lane [4K|4V] (8 lanes/head) -> dot=4 FMA, acc=4 FMA,
// all 64 lanes useful, 3 static xor-shuffles, no handoff. Edge loop processes
// groups of 4 with double-buffered gathers (4-8 outstanding misses/wave).
// No-max softmax (logits bounded); Q pre-scaled by log2e/sqrt32. CSR once.
// ---------------------------------------------------------------------------

#define NH 8
#define HCH 256
#define D32 32
#define INCH 63
#define CSCALE 0.25503485356f   // log2(e) / sqrt(32)

__device__ __forceinline__ unsigned short f2bf(float f) {
    unsigned u = __float_as_uint(f);
    u += 0x7fff + ((u >> 16) & 1);   // RNE
    return (unsigned short)(u >> 16);
}

// inv_freq[j] = 10000^(-2j/32) = 10^(-j/4)
__device__ const float c_invf[16] = {
    1.0f, 0.5623413251903491f, 0.31622776601683794f, 0.17782794100389228f,
    0.1f, 0.05623413251903491f, 0.031622776601683791f, 0.017782794100389228f,
    0.01f, 0.005623413251903491f, 0.0031622776601683794f, 0.0017782794100389228f,
    0.001f, 0.0005623413251903491f, 0.00031622776601683794f, 0.00017782794100389227f
};

// --- embed (+ fused skip-compose in 2 extra blocks) ------------------------
__global__ __launch_bounds__(256) void k_embed(
    const float* __restrict__ x, const float* __restrict__ W,
    const float* __restrict__ b, float* __restrict__ H, int N, int nbMain,
    const float* __restrict__ Wsk1, const float* __restrict__ bsk1,
    const float* __restrict__ Wh1,  const float* __restrict__ bh1,
    const float* __restrict__ Wsk2, const float* __restrict__ bsk2,
    const float* __restrict__ Wh2,  const float* __restrict__ bh2,
    float* __restrict__ WCB)
{
    if (blockIdx.x >= nbMain) {
        // compose: Wc = Ws@Wh (32x32), bc = bs@Wh + bh
        int lay = blockIdx.x - nbMain;
        const float* Wsk = lay ? Wsk2 : Wsk1;
        const float* bsk = lay ? bsk2 : bsk1;
        const float* Wh  = lay ? Wh2  : Wh1;
        const float* bh  = lay ? bh2  : bh1;
        float* o = WCB + lay * 1056;
        for (int i = threadIdx.x; i < D32 * D32 + D32; i += 256) {
            if (i < D32 * D32) {
                int r = i >> 5, c = i & 31;
                float a = 0.f;
                for (int k = 0; k < HCH; ++k) a = fmaf(Wsk[r * HCH + k], Wh[k * D32 + c], a);
                o[i] = a;
            } else {
                int c = i - D32 * D32;
                float a = bh[c];
                for (int k = 0; k < HCH; ++k) a = fmaf(bsk[k], Wh[k * D32 + c], a);
                o[1024 + c] = a;
            }
        }
        return;
    }
    __shared__ float xs[8][64];
    __shared__ float ws[INCH * D32];
    int row0 = blockIdx.x * 8;
    for (int i = threadIdx.x; i < INCH * D32; i += 256) ws[i] = W[i];
    for (int i = threadIdx.x; i < 8 * INCH; i += 256) {
        int r = i / INCH, cc = i % INCH;
        int gr = row0 + r;
        xs[r][cc] = (gr < N) ? x[(size_t)gr * INCH + cc] : 0.f;
    }
    __syncthreads();
    int lr = threadIdx.x >> 5, c = threadIdx.x & 31;
    int row = row0 + lr;
    if (row >= N) return;
    float acc = b[c];
#pragma unroll
    for (int k = 0; k < INCH; ++k) acc = fmaf(xs[lr][k], ws[k * D32 + c], acc);
    float phase = (float)row * c_invf[c >> 1];
    float pe = (c & 1) ? cosf(phase) : sinf(phase);
    H[(size_t)row * D32 + c] = acc + pe;
}

// --- CSR build -------------------------------------------------------------
__global__ void k_zero_i(int* __restrict__ p, int n) {
    int i = blockIdx.x * 256 + threadIdx.x;
    if (i < n) p[i] = 0;
}
__global__ void k_count(const int* __restrict__ dst, int* __restrict__ cnt, int E) {
    int i = blockIdx.x * 256 + threadIdx.x;
    if (i < E) atomicAdd(&cnt[dst[i]], 1);
}
// scan1 also emits DIS = rsqrt(deg+1)
__global__ void k_scan1(const int* __restrict__ cnt, int* __restrict__ rowptr,
                        int* __restrict__ partials, float* __restrict__ DIS, int N)
{
    __shared__ int s[256];
    int g = blockIdx.x * 256 + threadIdx.x;
    int myc = (g < N) ? cnt[g] : 0;
    if (g < N) DIS[g] = rsqrtf((float)myc + 1.0f);
    s[threadIdx.x] = myc;
    __syncthreads();
    for (int off = 1; off < 256; off <<= 1) {
        int t = (threadIdx.x >= off) ? s[threadIdx.x - off] : 0;
        __syncthreads();
        s[threadIdx.x] += t;
        __syncthreads();
    }
    if (g < N) rowptr[g + 1] = s[threadIdx.x];
    if (threadIdx.x == 255) partials[blockIdx.x] = s[255];
}
__global__ void k_scan2(int* __restrict__ partials, int nb) {
    __shared__ int s[256];
    int t = threadIdx.x;
    s[t] = (t < nb) ? partials[t] : 0;
    __syncthreads();
    for (int off = 1; off < 256; off <<= 1) {
        int v = (t >= off) ? s[t - off] : 0;
        __syncthreads();
        s[t] += v;
        __syncthreads();
    }
    partials[t] = (t == 0) ? 0 : s[t - 1];  // exclusive
}
// scan3 + setcur fused
__global__ void k_scan3b(int* __restrict__ rowptr, const int* __restrict__ partials,
                         int* __restrict__ cur, int N)
{
    int g = blockIdx.x * 256 + threadIdx.x;
    int add = partials[blockIdx.x];
    int oldprev = 0;
    if (g < N && threadIdx.x > 0) oldprev = rowptr[g];  // scan1's inclusive sum of tid-1
    __syncthreads();
    if (g < N) {
        rowptr[g + 1] += add;
        cur[g] = (threadIdx.x == 0) ? add : oldprev + add;
        if (g == 0) rowptr[0] = 0;
    }
}
__global__ void k_fill(const int* __restrict__ src, const int* __restrict__ dst,
                       int* __restrict__ cur, int* __restrict__ colsrc, int E)
{
    int e = blockIdx.x * 256 + threadIdx.x;
    if (e < E) {
        int p = atomicAdd(&cur[dst[e]], 1);
        colsrc[p] = src[e];
    }
}

// --- Q (fp32, pre-scaled), K/V (bf16, per-lane [4K|4V]), SKIP=H@Wc+bc ------
// KV row (512 ushort): lane l=8h+s owns ushort l*8..l*8+7 =
//   [K(h,s*4..s*4+3) | V(h,s*4..s*4+3)]
__global__ __launch_bounds__(256) void k_h32_to_kvqs(
    const float* __restrict__ Hm,
    const float* __restrict__ Wq, const float* __restrict__ bq,
    const float* __restrict__ Wk, const float* __restrict__ bk,
    const float* __restrict__ Wv, const float* __restrict__ bv,
    const float* __restrict__ WCBl,
    float* __restrict__ Q, unsigned short* __restrict__ KV,
    float* __restrict__ SKIP, int N)
{
    __shared__ float hs[8][33];
    int row0 = blockIdx.x * 8;
    int c = threadIdx.x;
    {
        int r = threadIdx.x >> 5, k = threadIdx.x & 31;
        int gr = row0 + r;
        hs[r][k] = (gr < N) ? Hm[(size_t)gr * D32 + k] : 0.f;
    }
    __syncthreads();
    float aQ[8], aK[8], aV[8], aS[8];
    float bQ = bq[c], bK = bk[c], bV = bv[c];
    float bS = (c < 32) ? WCBl[1024 + c] : 0.f;
#pragma unroll
    for (int r = 0; r < 8; ++r) { aQ[r] = bQ; aK[r] = bK; aV[r] = bV; aS[r] = bS; }
#pragma unroll 8
    for (int k = 0; k < 32; ++k) {
        float wq = Wq[k * HCH + c], wk = Wk[k * HCH + c], wv = Wv[k * HCH + c];
        float wc = (c < 32) ? WCBl[k * D32 + c] : 0.f;
#pragma unroll
        for (int r = 0; r < 8; ++r) {
            float h = hs[r][k];
            aQ[r] = fmaf(h, wq, aQ[r]);
            aK[r] = fmaf(h, wk, aK[r]);
            aV[r] = fmaf(h, wv, aV[r]);
            aS[r] = fmaf(h, wc, aS[r]);
        }
    }
    int hh = c >> 5, cc = c & 31, ss = cc >> 2, ii = cc & 3;
#pragma unroll
    for (int r = 0; r < 8; ++r) {
        int gr = row0 + r;
        if (gr < N) {
            Q[(size_t)gr * HCH + c] = aQ[r] * CSCALE;
            size_t kb = (size_t)gr * 512 + hh * 64 + ss * 8 + ii;
            KV[kb]     = f2bf(aK[r]);
            KV[kb + 4] = f2bf(aV[r]);
            if (c < 32) SKIP[(size_t)gr * D32 + c] = aS[r];
        }
    }
}

// --- fused attention: wave per dst node, group-of-4 double-buffered --------
#define PROC(A, PIDX)                                                        \
    {                                                                        \
        float f0 = __uint_as_float(A.x << 16);                               \
        float f1 = __uint_as_float(A.x & 0xffff0000u);                       \
        float f2 = __uint_as_float(A.y << 16);                               \
        float f3 = __uint_as_float(A.y & 0xffff0000u);                       \
        float t = q0 * f0 + q1 * f1 + q2 * f2 + q3 * f3;                     \
        t += __shfl_xor(t, 1, 64);                                           \
        t += __shfl_xor(t, 2, 64);                                           \
        t += __shfl_xor(t, 4, 64);                                           \
        float wg = ((PIDX) <= pl) ? exp2f(t) : 0.f;                          \
        l += wg;                                                             \
        acc0 = fmaf(wg, __uint_as_float(A.z << 16), acc0);                   \
        acc1 = fmaf(wg, __uint_as_float(A.z & 0xffff0000u), acc1);           \
        acc2 = fmaf(wg, __uint_as_float(A.w << 16), acc2);                   \
        acc3 = fmaf(wg, __uint_as_float(A.w & 0xffff0000u), acc3);           \
    }

__global__ __launch_bounds__(256) void k_attn(
    const uint4* __restrict__ KV4, const float4* __restrict__ Q4,
    const float* __restrict__ SKIP, float* __restrict__ H,
    const int* __restrict__ rowptr, const int* __restrict__ colsrc,
    const float* __restrict__ Wh, int N)
{
    __shared__ float os[4][264];
    int w = threadIdx.x >> 6, lane = threadIdx.x & 63;
    int d = blockIdx.x * 4 + w;
    bool act = d < N;

    float q0 = 0.f, q1 = 0.f, q2 = 0.f, q3 = 0.f;
    if (act) {
        float4 qv = Q4[(size_t)d * 64 + lane];
        q0 = qv.x; q1 = qv.y; q2 = qv.z; q3 = qv.w;
    }

    float l = 0.f, acc0 = 0.f, acc1 = 0.f, acc2 = 0.f, acc3 = 0.f;
    if (act) {
        int p0 = rowptr[d], p1 = rowptr[d + 1];
        if (p1 > p0) {
            int pl = p1 - 1;
            int s0 = colsrc[p0];
            int s1 = colsrc[p0 + 1 <= pl ? p0 + 1 : pl];
            int s2 = colsrc[p0 + 2 <= pl ? p0 + 2 : pl];
            int s3 = colsrc[p0 + 3 <= pl ? p0 + 3 : pl];
            uint4 A0 = KV4[(size_t)s0 * 64 + lane];
            uint4 A1 = KV4[(size_t)s1 * 64 + lane];
            uint4 A2 = KV4[(size_t)s2 * 64 + lane];
            uint4 A3 = KV4[(size_t)s3 * 64 + lane];
#pragma unroll 2
            for (int base = p0; base < p1; base += 4) {
                int nb = base + 4;
                int t0 = colsrc[nb     <= pl ? nb     : pl];
                int t1 = colsrc[nb + 1 <= pl ? nb + 1 : pl];
                int t2 = colsrc[nb + 2 <= pl ? nb + 2 : pl];
                int t3 = colsrc[nb + 3 <= pl ? nb + 3 : pl];
                uint4 B0 = KV4[(size_t)t0 * 64 + lane];
                uint4 B1 = KV4[(size_t)t1 * 64 + lane];
                uint4 B2 = KV4[(size_t)t2 * 64 + lane];
                uint4 B3 = KV4[(size_t)t3 * 64 + lane];
                PROC(A0, base)
                PROC(A1, base + 1)
                PROC(A2, base + 2)
                PROC(A3, base + 3)
                A0 = B0; A1 = B1; A2 = B2; A3 = B3;
            }
        }
        float inv = (l > 0.f) ? 1.f / l : 0.f;
        int gch = (lane >> 3) * 32 + (lane & 7) * 4;   // h*32 + s*4
        os[w][gch + 0] = acc0 * inv;
        os[w][gch + 1] = acc1 * inv;
        os[w][gch + 2] = acc2 * inv;
        os[w][gch + 3] = acc3 * inv;
    }
    __syncthreads();

    if (act) {
        int c = lane & 31, half = lane >> 5;
        float a2 = half ? 0.f : SKIP[(size_t)d * D32 + c];
        int kb = half * 128;
#pragma unroll 8
        for (int kk = 0; kk < 128; ++kk)
            a2 = fmaf(os[w][kb + kk], Wh[(kb + kk) * D32 + c], a2);
        a2 += __shfl_xor(a2, 32, 64);
        if (lane < 32) H[(size_t)d * D32 + c] = a2;
    }
}

// --- 32->32 matmul, output scaled by DIS[row] ------------------------------
__global__ __launch_bounds__(256) void k_h32_to_32s(
    const float* __restrict__ X, const float* __restrict__ W,
    const float* __restrict__ DIS, float* __restrict__ O, int N)
{
    __shared__ float xs[8][33];
    __shared__ float ws[D32 * D32];
    int row0 = blockIdx.x * 8;
    int c = threadIdx.x & 31, lr = threadIdx.x >> 5;
    for (int i = threadIdx.x; i < D32 * D32; i += 256) ws[i] = W[i];
    {
        int gr = row0 + lr;
        xs[lr][c] = (gr < N) ? X[(size_t)gr * D32 + c] : 0.f;
    }
    __syncthreads();
    int row = row0 + lr;
    if (row >= N) return;
    float acc = 0.f;
#pragma unroll
    for (int k = 0; k < D32; ++k) acc = fmaf(xs[lr][k], ws[k * D32 + c], acc);
    O[(size_t)row * D32 + c] = DIS[row] * acc;
}

// --- GCN gather (CSR): out = DIS[d]*(XWp[d] + sum_s XWp[s]) + b ------------
__global__ __launch_bounds__(256) void k_gcn(
    const float* __restrict__ XWp, const float* __restrict__ DIS,
    const int* __restrict__ rowptr, const int* __restrict__ colsrc,
    const float* __restrict__ b, float* __restrict__ Out, int N)
{
    int g = threadIdx.x >> 5;
    int c = threadIdx.x & 31;
    int d = blockIdx.x * 8 + g;
    if (d >= N) return;
    float acc = XWp[(size_t)d * D32 + c];
    int p0 = rowptr[d], p1 = rowptr[d + 1];
    if (p1 > p0) {
        int pl = p1 - 1;
        int sA = colsrc[p0];
        int sB = colsrc[p0 + 1 <= pl ? p0 + 1 : pl];
        int sC = colsrc[p0 + 2 <= pl ? p0 + 2 : pl];
        int sD = colsrc[p0 + 3 <= pl ? p0 + 3 : pl];
        float vA = XWp[(size_t)sA * D32 + c];
        float vB = XWp[(size_t)sB * D32 + c];
        float vC = XWp[(size_t)sC * D32 + c];
        float vD = XWp[(size_t)sD * D32 + c];
#pragma unroll 4
        for (int p = p0; p < p1; ++p) {
            int pn = p + 4 <= pl ? p + 4 : pl;
            int sN = colsrc[pn];
            float vN = XWp[(size_t)sN * D32 + c];
            acc += vA;
            vA = vB; vB = vC; vC = vD; vD = vN;
        }
    }
    Out[(size_t)d * D32 + c] = DIS[d] * acc + b[c];
}

// ---------------------------------------------------------------------------
extern "C" void kernel_launch(void* const* d_in, const int* in_sizes, int n_in,
                              void* d_out, int out_size, void* d_ws, size_t ws_size,
                              hipStream_t stream)
{
    const float* x  = (const float*)d_in[0];
    const int*   ei = (const int*)d_in[1];
    const int N = in_sizes[0] / INCH;
    const int E = in_sizes[1] / 2;
    const int* src = ei;
    const int* dst = ei + E;

    const float* W_embed = (const float*)d_in[2];
    const float* b_embed = (const float*)d_in[3];
    const float* Wg3 = (const float*)d_in[24];
    const float* bg3 = (const float*)d_in[25];
    const float* Wg4 = (const float*)d_in[26];
    const float* bg4 = (const float*)d_in[27];

    unsigned short* KV = (unsigned short*)d_ws;        // N*512 bf16
    float* Q      = (float*)(KV + (size_t)N * 512);    // N*256 f32
    float* H      = Q + (size_t)N * HCH;               // N*32
    float* A      = H + (size_t)N * D32;               // N*32 (SKIP / XWp)
    float* B      = A + (size_t)N * D32;               // N*32
    int*   rowptr = (int*)(B + (size_t)N * D32);       // N+1
    int*   colsrc = rowptr + (N + 1);                  // E
    int*   cursor = colsrc + E;                        // N
    int*   partials = cursor + N;                      // 256
    float* DIS    = (float*)(partials + 256);          // N
    float* WCB    = DIS + N;                           // 2*1056
    float* out    = (float*)d_out;

    const int nb8 = (N + 7) / 8;
    const int nbN = (N + 255) / 256;
    const int nbE = (E + 255) / 256;

    k_embed<<<nb8 + 2, 256, 0, stream>>>(
        x, W_embed, b_embed, H, N, nb8,
        (const float*)d_in[10], (const float*)d_in[11],
        (const float*)d_in[12], (const float*)d_in[13],
        (const float*)d_in[20], (const float*)d_in[21],
        (const float*)d_in[22], (const float*)d_in[23], WCB);

    k_zero_i<<<nbN, 256, 0, stream>>>(cursor, N);
    k_count<<<nbE, 256, 0, stream>>>(dst, cursor, E);
    k_scan1<<<nbN, 256, 0, stream>>>(cursor, rowptr, partials, DIS, N);
    k_scan2<<<1, 256, 0, stream>>>(partials, nbN);
    k_scan3b<<<nbN, 256, 0, stream>>>(rowptr, partials, cursor, N);
    k_fill<<<nbE, 256, 0, stream>>>(src, dst, cursor, colsrc, E);

    for (int layer = 0; layer < 2; ++layer) {
        int base = 4 + layer * 10;
        const float* Wq = (const float*)d_in[base + 0];
        const float* bq = (const float*)d_in[base + 1];
        const float* Wk = (const float*)d_in[base + 2];
        const float* bk = (const float*)d_in[base + 3];
        const float* Wv = (const float*)d_in[base + 4];
        const float* bv = (const float*)d_in[base + 5];
        const float* Wh = (const float*)d_in[base + 8];

        k_h32_to_kvqs<<<nb8, 256, 0, stream>>>(
            H, Wq, bq, Wk, bk, Wv, bv, WCB + layer * 1056, Q, KV, A, N);
        k_attn<<<(N + 3) / 4, 256, 0, stream>>>(
            (const uint4*)KV, (const float4*)Q, A, H, rowptr, colsrc, Wh, N);
    }

    k_h32_to_32s<<<nb8, 256, 0, stream>>>(H, Wg3, DIS, A, N);
    k_gcn<<<nb8, 256, 0, stream>>>(A, DIS, rowptr, colsrc, bg3, B, N);
    k_h32_to_32s<<<nb8, 256, 0, stream>>>(B, Wg4, DIS, A, N);
    k_gcn<<<nb8, 256, 0, stream>>>(A, DIS, rowptr, colsrc, bg4, out, N);
}